// Round 1
// baseline (1408.154 us; speedup 1.0000x reference)
//
#include <hip/hip_runtime.h>

#define NN 100000
#define NE 3200000

// ---------------- degree count ----------------
__global__ void count_deg(const int* __restrict__ dst, int* __restrict__ cnt, int E) {
    int e = blockIdx.x * 256 + threadIdx.x;
    if (e < E) atomicAdd(&cnt[dst[e]], 1);
}

// ---------------- single-block exclusive scan + dinv ----------------
__global__ void scan_deg(const int* __restrict__ cnt, int* __restrict__ rowptr,
                         float* __restrict__ dinv, int N) {
    __shared__ int s[1024];
    int t = threadIdx.x;
    const int per = (N + 1023) / 1024;  // 98
    int beg = t * per;
    int end = beg + per; if (end > N) end = N;
    int sum = 0;
    for (int i = beg; i < end; ++i) sum += cnt[i];
    s[t] = sum;
    __syncthreads();
    for (int off = 1; off < 1024; off <<= 1) {
        int v = s[t];
        int add = (t >= off) ? s[t - off] : 0;
        __syncthreads();
        s[t] = v + add;
        __syncthreads();
    }
    int run = s[t] - sum;  // exclusive prefix
    for (int i = beg; i < end; ++i) {
        rowptr[i] = run;
        int c = cnt[i];
        run += c;
        dinv[i] = 1.0f / sqrtf((float)(c + 1));  // +1 self-loop
    }
    if (t == 1023) rowptr[N] = s[1023];
}

// ---------------- CSR scatter ----------------
__global__ void scatter_edges(const int* __restrict__ src, const int* __restrict__ dst,
                              const int* __restrict__ rowptr, int* __restrict__ fill,
                              int* __restrict__ col, int E) {
    int e = blockIdx.x * 256 + threadIdx.x;
    if (e < E) {
        int d = dst[e];
        int p = rowptr[d] + atomicAdd(&fill[d], 1);
        col[p] = src[e];
    }
}

// ---------------- fp32 GEMM, N=128, templated K ----------------
// 64 rows x 128 cols per block, 256 threads, each thread 8x4 outputs.
template <int K>
__global__ __launch_bounds__(256) void gemm_n128(const float* __restrict__ X,
                                                 const float* __restrict__ W,
                                                 float* __restrict__ Y, int M) {
    __shared__ float xs[32][68];   // [k][row], transposed, padded
    __shared__ float ws[32][128];  // [k][n]
    int tid = threadIdx.x;
    int tx = tid & 31, ty = tid >> 5;
    int r0 = ty * 8, c0 = tx * 4;
    int rowBase = blockIdx.x * 64;

    float acc[8][4];
#pragma unroll
    for (int i = 0; i < 8; i++)
#pragma unroll
        for (int j = 0; j < 4; j++) acc[i][j] = 0.f;

    for (int kk = 0; kk < K; kk += 32) {
        // stage X tile (64 rows x 32 k) transposed into xs
#pragma unroll
        for (int l = 0; l < 2; l++) {
            int idx = tid + l * 256;
            int r = idx >> 3;   // 0..63
            int q = idx & 7;    // float4 index within 32-wide k strip
            int row = rowBase + r;
            float4 v = make_float4(0.f, 0.f, 0.f, 0.f);
            if (row < M) v = *reinterpret_cast<const float4*>(&X[row * K + kk + q * 4]);
            xs[q * 4 + 0][r] = v.x;
            xs[q * 4 + 1][r] = v.y;
            xs[q * 4 + 2][r] = v.z;
            xs[q * 4 + 3][r] = v.w;
        }
        // stage W tile (32 k x 128 n)
#pragma unroll
        for (int l = 0; l < 4; l++) {
            int idx = tid + l * 256;
            int kr = idx >> 5;  // 0..31
            int q = idx & 31;
            float4 v = *reinterpret_cast<const float4*>(&W[(kk + kr) * 128 + q * 4]);
            *reinterpret_cast<float4*>(&ws[kr][q * 4]) = v;
        }
        __syncthreads();
#pragma unroll
        for (int k = 0; k < 32; k++) {
            float4 b = *reinterpret_cast<const float4*>(&ws[k][c0]);
            float4 a0 = *reinterpret_cast<const float4*>(&xs[k][r0]);
            float4 a1 = *reinterpret_cast<const float4*>(&xs[k][r0 + 4]);
            float a[8] = {a0.x, a0.y, a0.z, a0.w, a1.x, a1.y, a1.z, a1.w};
#pragma unroll
            for (int i = 0; i < 8; i++) {
                acc[i][0] += a[i] * b.x;
                acc[i][1] += a[i] * b.y;
                acc[i][2] += a[i] * b.z;
                acc[i][3] += a[i] * b.w;
            }
        }
        __syncthreads();
    }
#pragma unroll
    for (int i = 0; i < 8; i++) {
        int row = rowBase + r0 + i;
        if (row < M) {
            float4 v = make_float4(acc[i][0], acc[i][1], acc[i][2], acc[i][3]);
            *reinterpret_cast<float4*>(&Y[row * 128 + c0]) = v;
        }
    }
}

// ---------------- small GEMM, N=5, K=128 ----------------
__global__ void gemm_n5(const float* __restrict__ X, const float* __restrict__ W,
                        float* __restrict__ Y, int M) {
    int idx = blockIdx.x * 256 + threadIdx.x;
    int row = idx / 5, c = idx % 5;
    if (row >= M) return;
    float acc = 0.f;
#pragma unroll 8
    for (int k = 0; k < 128; k++) acc += X[row * 128 + k] * W[k * 5 + c];
    Y[row * 5 + c] = acc;
}

// ---------------- CSR aggregation, dim 128: one wave per node ----------------
__global__ __launch_bounds__(256) void agg128(const float* __restrict__ h,
                                              const int* __restrict__ rowptr,
                                              const int* __restrict__ col,
                                              const float* __restrict__ dinv,
                                              const float* __restrict__ bias,
                                              float* __restrict__ out, int N, int do_relu) {
    int wave = threadIdx.x >> 6;
    int lane = threadIdx.x & 63;
    int node = blockIdx.x * 4 + wave;
    if (node >= N) return;
    const float2* __restrict__ h2 = reinterpret_cast<const float2*>(h);
    int beg = rowptr[node], end = rowptr[node + 1];
    float ax = 0.f, ay = 0.f;
    for (int j = beg; j < end; ++j) {
        int s = col[j];
        float w = dinv[s];
        float2 v = h2[s * 64 + lane];
        ax += v.x * w;
        ay += v.y * w;
    }
    float di = dinv[node];
    float2 self = h2[node * 64 + lane];
    float2 bb = reinterpret_cast<const float2*>(bias)[lane];
    float ox = ax * di + self.x * di * di + bb.x;
    float oy = ay * di + self.y * di * di + bb.y;
    if (do_relu) {
        ox = fmaxf(ox, 0.f);
        oy = fmaxf(oy, 0.f);
    }
    reinterpret_cast<float2*>(out)[node * 64 + lane] = make_float2(ox, oy);
}

// ---------------- CSR aggregation, dim 5: one thread per node ----------------
__global__ void agg5(const float* __restrict__ h, const int* __restrict__ rowptr,
                     const int* __restrict__ col, const float* __restrict__ dinv,
                     const float* __restrict__ b3, float* __restrict__ out, int N) {
    int node = blockIdx.x * 256 + threadIdx.x;
    if (node >= N) return;
    float acc[5] = {0.f, 0.f, 0.f, 0.f, 0.f};
    int beg = rowptr[node], end = rowptr[node + 1];
    for (int j = beg; j < end; ++j) {
        int s = col[j];
        float w = dinv[s];
#pragma unroll
        for (int f = 0; f < 5; f++) acc[f] += h[s * 5 + f] * w;
    }
    float di = dinv[node];
#pragma unroll
    for (int f = 0; f < 5; f++)
        out[node * 5 + f] = acc[f] * di + h[node * 5 + f] * di * di + b3[f];
}

static inline size_t align512(size_t x) { return (x + 511) & ~(size_t)511; }

extern "C" void kernel_launch(void* const* d_in, const int* in_sizes, int n_in,
                              void* d_out, int out_size, void* d_ws, size_t ws_size,
                              hipStream_t stream) {
    const float* x  = (const float*)d_in[0];
    const int* ei   = (const int*)d_in[1];
    const float* W1 = (const float*)d_in[2];
    const float* b1 = (const float*)d_in[3];
    const float* W2 = (const float*)d_in[4];
    const float* b2 = (const float*)d_in[5];
    const float* W3 = (const float*)d_in[6];
    const float* b3 = (const float*)d_in[7];
    const int* src = ei;
    const int* dst = ei + NE;

    char* ws = (char*)d_ws;
    size_t off = 0;
    int* cnt = (int*)(ws + off);        off += align512((size_t)NN * 4);
    int* rowptr = (int*)(ws + off);     off += align512((size_t)(NN + 1) * 4);
    float* dinv = (float*)(ws + off);   off += align512((size_t)NN * 4);
    int* col = (int*)(ws + off);        off += align512((size_t)NE * 4);
    float* bufA = (float*)(ws + off);   off += align512((size_t)NN * 128 * 4);
    float* bufB = (float*)(ws + off);   off += align512((size_t)NN * 128 * 4);
    float* bufC = (float*)(ws + off);   off += align512((size_t)NN * 5 * 4);
    (void)ws_size;

    // ---- build CSR (by dst) + dinv ----
    hipMemsetAsync(cnt, 0, (size_t)NN * 4, stream);
    count_deg<<<(NE + 255) / 256, 256, 0, stream>>>(dst, cnt, NE);
    scan_deg<<<1, 1024, 0, stream>>>(cnt, rowptr, dinv, NN);
    hipMemsetAsync(cnt, 0, (size_t)NN * 4, stream);
    scatter_edges<<<(NE + 255) / 256, 256, 0, stream>>>(src, dst, rowptr, cnt, col, NE);

    int gemm_blocks = (NN + 63) / 64;
    // ---- layer 1 ----
    gemm_n128<384><<<gemm_blocks, 256, 0, stream>>>(x, W1, bufA, NN);
    agg128<<<(NN + 3) / 4, 256, 0, stream>>>(bufA, rowptr, col, dinv, b1, bufB, NN, 1);
    // ---- layer 2 ----
    gemm_n128<128><<<gemm_blocks, 256, 0, stream>>>(bufB, W2, bufA, NN);
    agg128<<<(NN + 3) / 4, 256, 0, stream>>>(bufA, rowptr, col, dinv, b2, bufB, NN, 1);
    // ---- layer 3 ----
    gemm_n5<<<((NN * 5) + 255) / 256, 256, 0, stream>>>(bufB, W3, bufC, NN);
    agg5<<<(NN + 255) / 256, 256, 0, stream>>>(bufC, rowptr, col, dinv, b3, (float*)d_out, NN);
}

// Round 2
// 1084.227 us; speedup vs baseline: 1.2988x; 1.2988x over previous
//
#include <hip/hip_runtime.h>

#define NN 100000
#define NE 3200000

typedef unsigned int uint;
typedef unsigned short ushort;

// pack two fp32 -> two bf16 (RNE) in one uint (a = low, b = high)
__device__ inline uint bf16pair(float a, float b) {
    uint ua = __float_as_uint(a);
    uint ub = __float_as_uint(b);
    ua += 0x7FFFu + ((ua >> 16) & 1u);
    ub += 0x7FFFu + ((ub >> 16) & 1u);
    return (ua >> 16) | (ub & 0xFFFF0000u);
}

// ---------------- degree count ----------------
__global__ void count_deg(const int* __restrict__ dst, int* __restrict__ cnt, int E) {
    int e = blockIdx.x * 256 + threadIdx.x;
    if (e < E) atomicAdd(&cnt[dst[e]], 1);
}

// ---------------- single-block exclusive scan + dinv ----------------
__global__ void scan_deg(const int* __restrict__ cnt, int* __restrict__ rowptr,
                         float* __restrict__ dinv, int N) {
    __shared__ int s[1024];
    int t = threadIdx.x;
    const int per = (N + 1023) / 1024;
    int beg = t * per;
    int end = beg + per; if (end > N) end = N;
    int sum = 0;
    for (int i = beg; i < end; ++i) sum += cnt[i];
    s[t] = sum;
    __syncthreads();
    for (int off = 1; off < 1024; off <<= 1) {
        int v = s[t];
        int add = (t >= off) ? s[t - off] : 0;
        __syncthreads();
        s[t] = v + add;
        __syncthreads();
    }
    int run = s[t] - sum;
    for (int i = beg; i < end; ++i) {
        rowptr[i] = run;
        int c = cnt[i];
        run += c;
        dinv[i] = 1.0f / sqrtf((float)(c + 1));
    }
    if (t == 1023) rowptr[N] = s[1023];
}

// ---------------- CSR scatter ----------------
__global__ void scatter_edges(const int* __restrict__ src, const int* __restrict__ dst,
                              const int* __restrict__ rowptr, int* __restrict__ fill,
                              int* __restrict__ col, int E) {
    int e = blockIdx.x * 256 + threadIdx.x;
    if (e < E) {
        int d = dst[e];
        int p = rowptr[d] + atomicAdd(&fill[d], 1);
        col[p] = src[e];
    }
}

// ---------------- fp32 GEMM, N=128, templated K; output packed bf16 ----------------
template <int K>
__global__ __launch_bounds__(256) void gemm_n128_bf16out(const float* __restrict__ X,
                                                         const float* __restrict__ W,
                                                         uint* __restrict__ Y, int M) {
    __shared__ float xs[32][68];   // [k][row], transposed, padded
    __shared__ float ws[32][128];  // [k][n]
    int tid = threadIdx.x;
    int tx = tid & 31, ty = tid >> 5;
    int r0 = ty * 8, c0 = tx * 4;
    int rowBase = blockIdx.x * 64;

    float acc[8][4];
#pragma unroll
    for (int i = 0; i < 8; i++)
#pragma unroll
        for (int j = 0; j < 4; j++) acc[i][j] = 0.f;

    for (int kk = 0; kk < K; kk += 32) {
#pragma unroll
        for (int l = 0; l < 2; l++) {
            int idx = tid + l * 256;
            int r = idx >> 3;
            int q = idx & 7;
            int row = rowBase + r;
            float4 v = make_float4(0.f, 0.f, 0.f, 0.f);
            if (row < M) v = *reinterpret_cast<const float4*>(&X[row * K + kk + q * 4]);
            xs[q * 4 + 0][r] = v.x;
            xs[q * 4 + 1][r] = v.y;
            xs[q * 4 + 2][r] = v.z;
            xs[q * 4 + 3][r] = v.w;
        }
#pragma unroll
        for (int l = 0; l < 4; l++) {
            int idx = tid + l * 256;
            int kr = idx >> 5;
            int q = idx & 31;
            float4 v = *reinterpret_cast<const float4*>(&W[(kk + kr) * 128 + q * 4]);
            *reinterpret_cast<float4*>(&ws[kr][q * 4]) = v;
        }
        __syncthreads();
#pragma unroll
        for (int k = 0; k < 32; k++) {
            float4 b = *reinterpret_cast<const float4*>(&ws[k][c0]);
            float4 a0 = *reinterpret_cast<const float4*>(&xs[k][r0]);
            float4 a1 = *reinterpret_cast<const float4*>(&xs[k][r0 + 4]);
            float a[8] = {a0.x, a0.y, a0.z, a0.w, a1.x, a1.y, a1.z, a1.w};
#pragma unroll
            for (int i = 0; i < 8; i++) {
                acc[i][0] += a[i] * b.x;
                acc[i][1] += a[i] * b.y;
                acc[i][2] += a[i] * b.z;
                acc[i][3] += a[i] * b.w;
            }
        }
        __syncthreads();
    }
#pragma unroll
    for (int i = 0; i < 8; i++) {
        int row = rowBase + r0 + i;
        if (row < M) {
            uint2 v;
            v.x = bf16pair(acc[i][0], acc[i][1]);
            v.y = bf16pair(acc[i][2], acc[i][3]);
            // row stride = 64 uints (128 bf16); c0/2 = tx*2 uints
            *reinterpret_cast<uint2*>(&Y[row * 64 + tx * 2]) = v;
        }
    }
}

// ---------------- small GEMM, N=5, K=128 (fp32 in/out) ----------------
__global__ void gemm_n5(const float* __restrict__ X, const float* __restrict__ W,
                        float* __restrict__ Y, int M) {
    int idx = blockIdx.x * 256 + threadIdx.x;
    int row = idx / 5, c = idx % 5;
    if (row >= M) return;
    float acc = 0.f;
#pragma unroll 8
    for (int k = 0; k < 128; k++) acc += X[row * 128 + k] * W[k * 5 + c];
    Y[row * 5 + c] = acc;
}

// ---------------- CSR aggregation, dim 128, bf16 gather: one wave per node ----------------
__global__ __launch_bounds__(256) void agg128_bf16(const uint* __restrict__ hb,
                                                   const int* __restrict__ rowptr,
                                                   const int* __restrict__ col,
                                                   const float* __restrict__ dinv,
                                                   const float* __restrict__ bias,
                                                   float* __restrict__ out, int N, int do_relu) {
    int wave = threadIdx.x >> 6;
    int lane = threadIdx.x & 63;
    int node = blockIdx.x * 4 + wave;
    if (node >= N) return;
    int beg = rowptr[node], end = rowptr[node + 1];
    float ax = 0.f, ay = 0.f;
    int j = beg;
    int e4 = beg + ((end - beg) & ~3);
    for (; j < e4; j += 4) {
        int s0 = col[j], s1 = col[j + 1], s2 = col[j + 2], s3 = col[j + 3];
        float w0 = dinv[s0], w1 = dinv[s1], w2 = dinv[s2], w3 = dinv[s3];
        uint v0 = hb[s0 * 64 + lane];
        uint v1 = hb[s1 * 64 + lane];
        uint v2 = hb[s2 * 64 + lane];
        uint v3 = hb[s3 * 64 + lane];
        ax = fmaf(__uint_as_float(v0 << 16), w0, ax);
        ay = fmaf(__uint_as_float(v0 & 0xFFFF0000u), w0, ay);
        ax = fmaf(__uint_as_float(v1 << 16), w1, ax);
        ay = fmaf(__uint_as_float(v1 & 0xFFFF0000u), w1, ay);
        ax = fmaf(__uint_as_float(v2 << 16), w2, ax);
        ay = fmaf(__uint_as_float(v2 & 0xFFFF0000u), w2, ay);
        ax = fmaf(__uint_as_float(v3 << 16), w3, ax);
        ay = fmaf(__uint_as_float(v3 & 0xFFFF0000u), w3, ay);
    }
    for (; j < end; ++j) {
        int s = col[j];
        float w = dinv[s];
        uint v = hb[s * 64 + lane];
        ax = fmaf(__uint_as_float(v << 16), w, ax);
        ay = fmaf(__uint_as_float(v & 0xFFFF0000u), w, ay);
    }
    float di = dinv[node];
    uint vs = hb[node * 64 + lane];
    float sx = __uint_as_float(vs << 16);
    float sy = __uint_as_float(vs & 0xFFFF0000u);
    float2 bb = reinterpret_cast<const float2*>(bias)[lane];
    float ox = ax * di + sx * di * di + bb.x;
    float oy = ay * di + sy * di * di + bb.y;
    if (do_relu) {
        ox = fmaxf(ox, 0.f);
        oy = fmaxf(oy, 0.f);
    }
    reinterpret_cast<float2*>(out)[node * 64 + lane] = make_float2(ox, oy);
}

// ---------------- CSR aggregation, dim 5: one thread per node ----------------
__global__ void agg5(const float* __restrict__ h, const int* __restrict__ rowptr,
                     const int* __restrict__ col, const float* __restrict__ dinv,
                     const float* __restrict__ b3, float* __restrict__ out, int N) {
    int node = blockIdx.x * 256 + threadIdx.x;
    if (node >= N) return;
    float acc[5] = {0.f, 0.f, 0.f, 0.f, 0.f};
    int beg = rowptr[node], end = rowptr[node + 1];
    for (int j = beg; j < end; ++j) {
        int s = col[j];
        float w = dinv[s];
#pragma unroll
        for (int f = 0; f < 5; f++) acc[f] += h[s * 5 + f] * w;
    }
    float di = dinv[node];
#pragma unroll
    for (int f = 0; f < 5; f++)
        out[node * 5 + f] = acc[f] * di + h[node * 5 + f] * di * di + b3[f];
}

static inline size_t align512(size_t x) { return (x + 511) & ~(size_t)511; }

extern "C" void kernel_launch(void* const* d_in, const int* in_sizes, int n_in,
                              void* d_out, int out_size, void* d_ws, size_t ws_size,
                              hipStream_t stream) {
    const float* x  = (const float*)d_in[0];
    const int* ei   = (const int*)d_in[1];
    const float* W1 = (const float*)d_in[2];
    const float* b1 = (const float*)d_in[3];
    const float* W2 = (const float*)d_in[4];
    const float* b2 = (const float*)d_in[5];
    const float* W3 = (const float*)d_in[6];
    const float* b3 = (const float*)d_in[7];
    const int* src = ei;
    const int* dst = ei + NE;

    char* ws = (char*)d_ws;
    size_t off = 0;
    int* cnt = (int*)(ws + off);        off += align512((size_t)NN * 4);
    int* rowptr = (int*)(ws + off);     off += align512((size_t)(NN + 1) * 4);
    float* dinv = (float*)(ws + off);   off += align512((size_t)NN * 4);
    int* col = (int*)(ws + off);        off += align512((size_t)NE * 4);
    uint* hb = (uint*)(ws + off);       off += align512((size_t)NN * 64 * 4);   // bf16 h (packed)
    float* bufF = (float*)(ws + off);   off += align512((size_t)NN * 128 * 4);  // fp32 agg out
    float* bufC = (float*)(ws + off);   off += align512((size_t)NN * 5 * 4);
    (void)ws_size;

    // ---- build CSR (by dst) + dinv ----
    hipMemsetAsync(cnt, 0, (size_t)NN * 4, stream);
    count_deg<<<(NE + 255) / 256, 256, 0, stream>>>(dst, cnt, NE);
    scan_deg<<<1, 1024, 0, stream>>>(cnt, rowptr, dinv, NN);
    hipMemsetAsync(cnt, 0, (size_t)NN * 4, stream);
    scatter_edges<<<(NE + 255) / 256, 256, 0, stream>>>(src, dst, rowptr, cnt, col, NE);

    int gemm_blocks = (NN + 63) / 64;
    // ---- layer 1 ----
    gemm_n128_bf16out<384><<<gemm_blocks, 256, 0, stream>>>(x, W1, hb, NN);
    agg128_bf16<<<(NN + 3) / 4, 256, 0, stream>>>(hb, rowptr, col, dinv, b1, bufF, NN, 1);
    // ---- layer 2 ----
    gemm_n128_bf16out<128><<<gemm_blocks, 256, 0, stream>>>(bufF, W2, hb, NN);
    agg128_bf16<<<(NN + 3) / 4, 256, 0, stream>>>(hb, rowptr, col, dinv, b2, bufF, NN, 1);
    // ---- layer 3 ----
    gemm_n5<<<((NN * 5) + 255) / 256, 256, 0, stream>>>(bufF, W3, bufC, NN);
    agg5<<<(NN + 255) / 256, 256, 0, stream>>>(bufC, rowptr, col, dinv, b3, (float*)d_out, NN);
}

// Round 3
// 870.695 us; speedup vs baseline: 1.6173x; 1.2452x over previous
//
#include <hip/hip_runtime.h>

#define NN 100000
#define NE 3200000
#define SCAN_CHUNK 1024
#define NBLK ((NN + SCAN_CHUNK - 1) / SCAN_CHUNK)  // 98

typedef unsigned int uint;

// pack two fp32 -> two bf16 (RNE) in one uint (a = low, b = high)
__device__ inline uint bf16pair(float a, float b) {
    uint ua = __float_as_uint(a);
    uint ub = __float_as_uint(b);
    ua += 0x7FFFu + ((ua >> 16) & 1u);
    ub += 0x7FFFu + ((ub >> 16) & 1u);
    return (ua >> 16) | (ub & 0xFFFF0000u);
}

// ---------------- degree count ----------------
__global__ void count_deg(const int* __restrict__ dst, int* __restrict__ cnt, int E) {
    int e = blockIdx.x * 256 + threadIdx.x;
    if (e < E) atomicAdd(&cnt[dst[e]], 1);
}

// ---------------- hierarchical scan: phase 1 (per-block sums) ----------------
__global__ __launch_bounds__(256) void scan_p1(const int* __restrict__ cnt,
                                               int* __restrict__ bsum, int N) {
    int t = threadIdx.x;
    int base = blockIdx.x * SCAN_CHUNK + t * 4;
    int s = 0;
#pragma unroll
    for (int q = 0; q < 4; q++) {
        int i = base + q;
        if (i < N) s += cnt[i];
    }
    __shared__ int red[4];
#pragma unroll
    for (int off = 32; off; off >>= 1) s += __shfl_down(s, off, 64);
    if ((t & 63) == 0) red[t >> 6] = s;
    __syncthreads();
    if (t == 0) bsum[blockIdx.x] = red[0] + red[1] + red[2] + red[3];
}

// ---------------- phase 2: exclusive scan of block sums (single tiny block) ----------------
__global__ void scan_p2(int* __restrict__ bsum, int nb) {
    __shared__ int s[128];
    int t = threadIdx.x;
    int v = (t < nb) ? bsum[t] : 0;
    s[t] = v;
    __syncthreads();
    for (int off = 1; off < 128; off <<= 1) {
        int x = s[t];
        int add = (t >= off) ? s[t - off] : 0;
        __syncthreads();
        s[t] = x + add;
        __syncthreads();
    }
    if (t < nb) bsum[t] = s[t] - v;  // exclusive
}

// ---------------- phase 3: local scan + offset, write rowptr & dinv ----------------
__global__ __launch_bounds__(256) void scan_p3(const int* __restrict__ cnt,
                                               const int* __restrict__ bsum,
                                               int* __restrict__ rowptr,
                                               float* __restrict__ dinv, int N) {
    __shared__ int ts[256];
    int t = threadIdx.x;
    int base = blockIdx.x * SCAN_CHUNK + t * 4;
    int c[4];
    int s = 0;
#pragma unroll
    for (int q = 0; q < 4; q++) {
        int i = base + q;
        c[q] = (i < N) ? cnt[i] : 0;
        s += c[q];
    }
    ts[t] = s;
    __syncthreads();
    for (int off = 1; off < 256; off <<= 1) {
        int x = ts[t];
        int add = (t >= off) ? ts[t - off] : 0;
        __syncthreads();
        ts[t] = x + add;
        __syncthreads();
    }
    int run = bsum[blockIdx.x] + ts[t] - s;  // exclusive prefix for this thread's range
#pragma unroll
    for (int q = 0; q < 4; q++) {
        int i = base + q;
        if (i < N) {
            rowptr[i] = run;
            dinv[i] = 1.0f / sqrtf((float)(c[q] + 1));  // +1 self-loop
            run += c[q];
        }
    }
    if (base < N && N <= base + 4) rowptr[N] = run;  // thread owning last element writes total
}

// ---------------- CSR scatter ----------------
__global__ void scatter_edges(const int* __restrict__ src, const int* __restrict__ dst,
                              const int* __restrict__ rowptr, int* __restrict__ fill,
                              int* __restrict__ col, int E) {
    int e = blockIdx.x * 256 + threadIdx.x;
    if (e < E) {
        int d = dst[e];
        int p = rowptr[d] + atomicAdd(&fill[d], 1);
        col[p] = src[e];
    }
}

// ---------------- fp32 GEMM, N=128, templated K; output packed bf16 ----------------
template <int K>
__global__ __launch_bounds__(256) void gemm_n128_bf16out(const float* __restrict__ X,
                                                         const float* __restrict__ W,
                                                         uint* __restrict__ Y, int M) {
    __shared__ float xs[32][68];   // [k][row], transposed, padded
    __shared__ float ws[32][128];  // [k][n]
    int tid = threadIdx.x;
    int tx = tid & 31, ty = tid >> 5;
    int r0 = ty * 8, c0 = tx * 4;
    int rowBase = blockIdx.x * 64;

    float acc[8][4];
#pragma unroll
    for (int i = 0; i < 8; i++)
#pragma unroll
        for (int j = 0; j < 4; j++) acc[i][j] = 0.f;

    for (int kk = 0; kk < K; kk += 32) {
#pragma unroll
        for (int l = 0; l < 2; l++) {
            int idx = tid + l * 256;
            int r = idx >> 3;
            int q = idx & 7;
            int row = rowBase + r;
            float4 v = make_float4(0.f, 0.f, 0.f, 0.f);
            if (row < M) v = *reinterpret_cast<const float4*>(&X[row * K + kk + q * 4]);
            xs[q * 4 + 0][r] = v.x;
            xs[q * 4 + 1][r] = v.y;
            xs[q * 4 + 2][r] = v.z;
            xs[q * 4 + 3][r] = v.w;
        }
#pragma unroll
        for (int l = 0; l < 4; l++) {
            int idx = tid + l * 256;
            int kr = idx >> 5;
            int q = idx & 31;
            float4 v = *reinterpret_cast<const float4*>(&W[(kk + kr) * 128 + q * 4]);
            *reinterpret_cast<float4*>(&ws[kr][q * 4]) = v;
        }
        __syncthreads();
#pragma unroll
        for (int k = 0; k < 32; k++) {
            float4 b = *reinterpret_cast<const float4*>(&ws[k][c0]);
            float4 a0 = *reinterpret_cast<const float4*>(&xs[k][r0]);
            float4 a1 = *reinterpret_cast<const float4*>(&xs[k][r0 + 4]);
            float a[8] = {a0.x, a0.y, a0.z, a0.w, a1.x, a1.y, a1.z, a1.w};
#pragma unroll
            for (int i = 0; i < 8; i++) {
                acc[i][0] += a[i] * b.x;
                acc[i][1] += a[i] * b.y;
                acc[i][2] += a[i] * b.z;
                acc[i][3] += a[i] * b.w;
            }
        }
        __syncthreads();
    }
#pragma unroll
    for (int i = 0; i < 8; i++) {
        int row = rowBase + r0 + i;
        if (row < M) {
            uint2 v;
            v.x = bf16pair(acc[i][0], acc[i][1]);
            v.y = bf16pair(acc[i][2], acc[i][3]);
            *reinterpret_cast<uint2*>(&Y[row * 64 + tx * 2]) = v;
        }
    }
}

// ---------------- small GEMM, N=5, K=128 (fp32 in/out) ----------------
__global__ void gemm_n5(const float* __restrict__ X, const float* __restrict__ W,
                        float* __restrict__ Y, int M) {
    int idx = blockIdx.x * 256 + threadIdx.x;
    int row = idx / 5, c = idx % 5;
    if (row >= M) return;
    float acc = 0.f;
#pragma unroll 8
    for (int k = 0; k < 128; k++) acc += X[row * 128 + k] * W[k * 5 + c];
    Y[row * 5 + c] = acc;
}

// ---------------- CSR aggregation, dim 128, bf16 gather: one wave per node ----------------
__global__ __launch_bounds__(256) void agg128_bf16(const uint* __restrict__ hb,
                                                   const int* __restrict__ rowptr,
                                                   const int* __restrict__ col,
                                                   const float* __restrict__ dinv,
                                                   const float* __restrict__ bias,
                                                   float* __restrict__ out, int N, int do_relu) {
    int wave = threadIdx.x >> 6;
    int lane = threadIdx.x & 63;
    int node = blockIdx.x * 4 + wave;
    if (node >= N) return;
    int beg = rowptr[node], end = rowptr[node + 1];
    float ax = 0.f, ay = 0.f;
    int j = beg;
    int e4 = beg + ((end - beg) & ~3);
    for (; j < e4; j += 4) {
        int s0 = col[j], s1 = col[j + 1], s2 = col[j + 2], s3 = col[j + 3];
        float w0 = dinv[s0], w1 = dinv[s1], w2 = dinv[s2], w3 = dinv[s3];
        uint v0 = hb[s0 * 64 + lane];
        uint v1 = hb[s1 * 64 + lane];
        uint v2 = hb[s2 * 64 + lane];
        uint v3 = hb[s3 * 64 + lane];
        ax = fmaf(__uint_as_float(v0 << 16), w0, ax);
        ay = fmaf(__uint_as_float(v0 & 0xFFFF0000u), w0, ay);
        ax = fmaf(__uint_as_float(v1 << 16), w1, ax);
        ay = fmaf(__uint_as_float(v1 & 0xFFFF0000u), w1, ay);
        ax = fmaf(__uint_as_float(v2 << 16), w2, ax);
        ay = fmaf(__uint_as_float(v2 & 0xFFFF0000u), w2, ay);
        ax = fmaf(__uint_as_float(v3 << 16), w3, ax);
        ay = fmaf(__uint_as_float(v3 & 0xFFFF0000u), w3, ay);
    }
    for (; j < end; ++j) {
        int s = col[j];
        float w = dinv[s];
        uint v = hb[s * 64 + lane];
        ax = fmaf(__uint_as_float(v << 16), w, ax);
        ay = fmaf(__uint_as_float(v & 0xFFFF0000u), w, ay);
    }
    float di = dinv[node];
    uint vs = hb[node * 64 + lane];
    float sx = __uint_as_float(vs << 16);
    float sy = __uint_as_float(vs & 0xFFFF0000u);
    float2 bb = reinterpret_cast<const float2*>(bias)[lane];
    float ox = ax * di + sx * di * di + bb.x;
    float oy = ay * di + sy * di * di + bb.y;
    if (do_relu) {
        ox = fmaxf(ox, 0.f);
        oy = fmaxf(oy, 0.f);
    }
    reinterpret_cast<float2*>(out)[node * 64 + lane] = make_float2(ox, oy);
}

// ---------------- CSR aggregation, dim 5: one thread per node ----------------
__global__ void agg5(const float* __restrict__ h, const int* __restrict__ rowptr,
                     const int* __restrict__ col, const float* __restrict__ dinv,
                     const float* __restrict__ b3, float* __restrict__ out, int N) {
    int node = blockIdx.x * 256 + threadIdx.x;
    if (node >= N) return;
    float acc[5] = {0.f, 0.f, 0.f, 0.f, 0.f};
    int beg = rowptr[node], end = rowptr[node + 1];
    for (int j = beg; j < end; ++j) {
        int s = col[j];
        float w = dinv[s];
#pragma unroll
        for (int f = 0; f < 5; f++) acc[f] += h[s * 5 + f] * w;
    }
    float di = dinv[node];
#pragma unroll
    for (int f = 0; f < 5; f++)
        out[node * 5 + f] = acc[f] * di + h[node * 5 + f] * di * di + b3[f];
}

static inline size_t align512(size_t x) { return (x + 511) & ~(size_t)511; }

extern "C" void kernel_launch(void* const* d_in, const int* in_sizes, int n_in,
                              void* d_out, int out_size, void* d_ws, size_t ws_size,
                              hipStream_t stream) {
    const float* x  = (const float*)d_in[0];
    const int* ei   = (const int*)d_in[1];
    const float* W1 = (const float*)d_in[2];
    const float* b1 = (const float*)d_in[3];
    const float* W2 = (const float*)d_in[4];
    const float* b2 = (const float*)d_in[5];
    const float* W3 = (const float*)d_in[6];
    const float* b3 = (const float*)d_in[7];
    const int* src = ei;
    const int* dst = ei + NE;

    char* ws = (char*)d_ws;
    size_t off = 0;
    int* cnt = (int*)(ws + off);        off += align512((size_t)NN * 4);
    int* rowptr = (int*)(ws + off);     off += align512((size_t)(NN + 1) * 4);
    float* dinv = (float*)(ws + off);   off += align512((size_t)NN * 4);
    int* bsum = (int*)(ws + off);       off += align512((size_t)NBLK * 4);
    int* col = (int*)(ws + off);        off += align512((size_t)NE * 4);
    uint* hb = (uint*)(ws + off);       off += align512((size_t)NN * 64 * 4);   // bf16 h (packed)
    float* bufF = (float*)(ws + off);   off += align512((size_t)NN * 128 * 4);  // fp32 agg out
    float* bufC = (float*)(ws + off);   off += align512((size_t)NN * 5 * 4);
    (void)ws_size;

    // ---- build CSR (by dst) + dinv ----
    hipMemsetAsync(cnt, 0, (size_t)NN * 4, stream);
    count_deg<<<(NE + 255) / 256, 256, 0, stream>>>(dst, cnt, NE);
    scan_p1<<<NBLK, 256, 0, stream>>>(cnt, bsum, NN);
    scan_p2<<<1, 128, 0, stream>>>(bsum, NBLK);
    scan_p3<<<NBLK, 256, 0, stream>>>(cnt, bsum, rowptr, dinv, NN);
    hipMemsetAsync(cnt, 0, (size_t)NN * 4, stream);
    scatter_edges<<<(NE + 255) / 256, 256, 0, stream>>>(src, dst, rowptr, cnt, col, NE);

    int gemm_blocks = (NN + 63) / 64;
    // ---- layer 1 ----
    gemm_n128_bf16out<384><<<gemm_blocks, 256, 0, stream>>>(x, W1, hb, NN);
    agg128_bf16<<<(NN + 3) / 4, 256, 0, stream>>>(hb, rowptr, col, dinv, b1, bufF, NN, 1);
    // ---- layer 2 ----
    gemm_n128_bf16out<128><<<gemm_blocks, 256, 0, stream>>>(bufF, W2, hb, NN);
    agg128_bf16<<<(NN + 3) / 4, 256, 0, stream>>>(hb, rowptr, col, dinv, b2, bufF, NN, 1);
    // ---- layer 3 ----
    gemm_n5<<<((NN * 5) + 255) / 256, 256, 0, stream>>>(bufF, W3, bufC, NN);
    agg5<<<(NN + 255) / 256, 256, 0, stream>>>(bufC, rowptr, col, dinv, b3, (float*)d_out, NN);
}

// Round 4
// 661.055 us; speedup vs baseline: 2.1302x; 1.3171x over previous
//
#include <hip/hip_runtime.h>

#define NN 100000
#define NE 3200000
#define SCAN_CHUNK 1024

// bucket sort params
#define BSH 8
#define BKT_NODES 256                       // 1 << BSH
#define NBKT ((NN + BKT_NODES - 1) / BKT_NODES)   // 391
#define BIN_BLOCKS 256
#define EPB ((NE + BIN_BLOCKS - 1) / BIN_BLOCKS)  // 12500
#define GH (NBKT * BIN_BLOCKS)                    // 100096

typedef unsigned int uint;

// pack two fp32 -> two bf16 (RNE) in one uint (a = low, b = high)
__device__ inline uint bf16pair(float a, float b) {
    uint ua = __float_as_uint(a);
    uint ub = __float_as_uint(b);
    ua += 0x7FFFu + ((ua >> 16) & 1u);
    ub += 0x7FFFu + ((ub >> 16) & 1u);
    return (ua >> 16) | (ub & 0xFFFF0000u);
}

// ---------------- bucket histogram (per binning-block, bucket-major out) ----------------
__global__ __launch_bounds__(256) void hist_bkt(const int* __restrict__ dst,
                                                int* __restrict__ ghist) {
    __shared__ int h[NBKT];
    int t = threadIdx.x;
    for (int i = t; i < NBKT; i += 256) h[i] = 0;
    __syncthreads();
    int beg = blockIdx.x * EPB;
    int end = beg + EPB; if (end > NE) end = NE;
    for (int e = beg + t; e < end; e += 256)
        atomicAdd(&h[dst[e] >> BSH], 1);
    __syncthreads();
    for (int i = t; i < NBKT; i += 256)
        ghist[i * BIN_BLOCKS + blockIdx.x] = h[i];
}

// ---------------- hierarchical scan: phase 1 (per-block sums) ----------------
__global__ __launch_bounds__(256) void scan_p1(const int* __restrict__ cnt,
                                               int* __restrict__ bsum, int N) {
    int t = threadIdx.x;
    int base = blockIdx.x * SCAN_CHUNK + t * 4;
    int s = 0;
#pragma unroll
    for (int q = 0; q < 4; q++) {
        int i = base + q;
        if (i < N) s += cnt[i];
    }
    __shared__ int red[4];
#pragma unroll
    for (int off = 32; off; off >>= 1) s += __shfl_down(s, off, 64);
    if ((t & 63) == 0) red[t >> 6] = s;
    __syncthreads();
    if (t == 0) bsum[blockIdx.x] = red[0] + red[1] + red[2] + red[3];
}

// ---------------- phase 2: exclusive scan of block sums (single tiny block) ----------------
__global__ void scan_p2(int* __restrict__ bsum, int nb) {
    __shared__ int s[128];
    int t = threadIdx.x;
    int v = (t < nb) ? bsum[t] : 0;
    s[t] = v;
    __syncthreads();
    for (int off = 1; off < 128; off <<= 1) {
        int x = s[t];
        int add = (t >= off) ? s[t - off] : 0;
        __syncthreads();
        s[t] = x + add;
        __syncthreads();
    }
    if (t < nb) bsum[t] = s[t] - v;  // exclusive
}

// ---------------- phase 3a: in-place exclusive scan ----------------
__global__ __launch_bounds__(256) void scan_p3_plain(int* __restrict__ data,
                                                     const int* __restrict__ bsum, int N) {
    __shared__ int ts[256];
    int t = threadIdx.x;
    int base = blockIdx.x * SCAN_CHUNK + t * 4;
    int c[4];
    int s = 0;
#pragma unroll
    for (int q = 0; q < 4; q++) {
        int i = base + q;
        c[q] = (i < N) ? data[i] : 0;
        s += c[q];
    }
    ts[t] = s;
    __syncthreads();
    for (int off = 1; off < 256; off <<= 1) {
        int x = ts[t];
        int add = (t >= off) ? ts[t - off] : 0;
        __syncthreads();
        ts[t] = x + add;
        __syncthreads();
    }
    int run = bsum[blockIdx.x] + ts[t] - s;
#pragma unroll
    for (int q = 0; q < 4; q++) {
        int i = base + q;
        if (i < N) { data[i] = run; run += c[q]; }
    }
}

// ---------------- phase 3b: scan + rowptr + dinv ----------------
__global__ __launch_bounds__(256) void scan_p3_deg(const int* __restrict__ cnt,
                                                   const int* __restrict__ bsum,
                                                   int* __restrict__ rowptr,
                                                   float* __restrict__ dinv, int N) {
    __shared__ int ts[256];
    int t = threadIdx.x;
    int base = blockIdx.x * SCAN_CHUNK + t * 4;
    int c[4];
    int s = 0;
#pragma unroll
    for (int q = 0; q < 4; q++) {
        int i = base + q;
        c[q] = (i < N) ? cnt[i] : 0;
        s += c[q];
    }
    ts[t] = s;
    __syncthreads();
    for (int off = 1; off < 256; off <<= 1) {
        int x = ts[t];
        int add = (t >= off) ? ts[t - off] : 0;
        __syncthreads();
        ts[t] = x + add;
        __syncthreads();
    }
    int run = bsum[blockIdx.x] + ts[t] - s;
#pragma unroll
    for (int q = 0; q < 4; q++) {
        int i = base + q;
        if (i < N) {
            rowptr[i] = run;
            dinv[i] = 1.0f / sqrtf((float)(c[q] + 1));  // +1 self-loop
            run += c[q];
        }
    }
    if (base < N && N <= base + 4) rowptr[N] = run;
}

// ---------------- bin edges into bucket-segmented records ----------------
__global__ __launch_bounds__(256) void bin_edges(const int* __restrict__ src,
                                                 const int* __restrict__ dst,
                                                 const int* __restrict__ ghist,
                                                 uint* __restrict__ binned) {
    __shared__ int cur[NBKT];
    int t = threadIdx.x;
    for (int i = t; i < NBKT; i += 256) cur[i] = ghist[i * BIN_BLOCKS + blockIdx.x];
    __syncthreads();
    int beg = blockIdx.x * EPB;
    int end = beg + EPB; if (end > NE) end = NE;
    for (int e = beg + t; e < end; e += 256) {
        int d = dst[e];
        int b = d >> BSH;
        int p = atomicAdd(&cur[b], 1);
        binned[p] = ((uint)src[e] << BSH) | (uint)(d & (BKT_NODES - 1));
    }
}

// ---------------- per-bucket node degree count ----------------
__global__ __launch_bounds__(256) void bucket_count(const uint* __restrict__ binned,
                                                    const int* __restrict__ ghist,
                                                    int* __restrict__ cnt) {
    __shared__ int c[BKT_NODES];
    int t = threadIdx.x;
    int bkt = blockIdx.x;
    for (int i = t; i < BKT_NODES; i += 256) c[i] = 0;
    __syncthreads();
    int beg = ghist[bkt * BIN_BLOCKS];
    int end = (bkt == NBKT - 1) ? NE : ghist[(bkt + 1) * BIN_BLOCKS];
    for (int j = beg + t; j < end; j += 256)
        atomicAdd(&c[binned[j] & (BKT_NODES - 1)], 1);
    __syncthreads();
    int base = bkt * BKT_NODES;
    int nb = NN - base; if (nb > BKT_NODES) nb = BKT_NODES;
    for (int i = t; i < nb; i += 256) cnt[base + i] = c[i];
}

// ---------------- per-bucket CSR fill ----------------
__global__ __launch_bounds__(256) void csr_fill(const uint* __restrict__ binned,
                                                const int* __restrict__ ghist,
                                                const int* __restrict__ rowptr,
                                                int* __restrict__ col) {
    __shared__ int fill[BKT_NODES];
    int t = threadIdx.x;
    int bkt = blockIdx.x;
    for (int i = t; i < BKT_NODES; i += 256) fill[i] = 0;
    __syncthreads();
    int beg = ghist[bkt * BIN_BLOCKS];
    int end = (bkt == NBKT - 1) ? NE : ghist[(bkt + 1) * BIN_BLOCKS];
    int base = bkt * BKT_NODES;
    for (int j = beg + t; j < end; j += 256) {
        uint r = binned[j];
        int dl = r & (BKT_NODES - 1);
        int p = rowptr[base + dl] + atomicAdd(&fill[dl], 1);
        col[p] = (int)(r >> BSH);
    }
}

// ---------------- fp32 GEMM, N=128, templated K; output packed bf16 ----------------
template <int K>
__global__ __launch_bounds__(256) void gemm_n128_bf16out(const float* __restrict__ X,
                                                         const float* __restrict__ W,
                                                         uint* __restrict__ Y, int M) {
    __shared__ float xs[32][68];   // [k][row], transposed, padded
    __shared__ float ws[32][128];  // [k][n]
    int tid = threadIdx.x;
    int tx = tid & 31, ty = tid >> 5;
    int r0 = ty * 8, c0 = tx * 4;
    int rowBase = blockIdx.x * 64;

    float acc[8][4];
#pragma unroll
    for (int i = 0; i < 8; i++)
#pragma unroll
        for (int j = 0; j < 4; j++) acc[i][j] = 0.f;

    for (int kk = 0; kk < K; kk += 32) {
#pragma unroll
        for (int l = 0; l < 2; l++) {
            int idx = tid + l * 256;
            int r = idx >> 3;
            int q = idx & 7;
            int row = rowBase + r;
            float4 v = make_float4(0.f, 0.f, 0.f, 0.f);
            if (row < M) v = *reinterpret_cast<const float4*>(&X[row * K + kk + q * 4]);
            xs[q * 4 + 0][r] = v.x;
            xs[q * 4 + 1][r] = v.y;
            xs[q * 4 + 2][r] = v.z;
            xs[q * 4 + 3][r] = v.w;
        }
#pragma unroll
        for (int l = 0; l < 4; l++) {
            int idx = tid + l * 256;
            int kr = idx >> 5;
            int q = idx & 31;
            float4 v = *reinterpret_cast<const float4*>(&W[(kk + kr) * 128 + q * 4]);
            *reinterpret_cast<float4*>(&ws[kr][q * 4]) = v;
        }
        __syncthreads();
#pragma unroll
        for (int k = 0; k < 32; k++) {
            float4 b = *reinterpret_cast<const float4*>(&ws[k][c0]);
            float4 a0 = *reinterpret_cast<const float4*>(&xs[k][r0]);
            float4 a1 = *reinterpret_cast<const float4*>(&xs[k][r0 + 4]);
            float a[8] = {a0.x, a0.y, a0.z, a0.w, a1.x, a1.y, a1.z, a1.w};
#pragma unroll
            for (int i = 0; i < 8; i++) {
                acc[i][0] += a[i] * b.x;
                acc[i][1] += a[i] * b.y;
                acc[i][2] += a[i] * b.z;
                acc[i][3] += a[i] * b.w;
            }
        }
        __syncthreads();
    }
#pragma unroll
    for (int i = 0; i < 8; i++) {
        int row = rowBase + r0 + i;
        if (row < M) {
            uint2 v;
            v.x = bf16pair(acc[i][0], acc[i][1]);
            v.y = bf16pair(acc[i][2], acc[i][3]);
            *reinterpret_cast<uint2*>(&Y[row * 64 + tx * 2]) = v;
        }
    }
}

// ---------------- small GEMM, N=5, K=128 (fp32 in/out) ----------------
__global__ void gemm_n5(const float* __restrict__ X, const float* __restrict__ W,
                        float* __restrict__ Y, int M) {
    int idx = blockIdx.x * 256 + threadIdx.x;
    int row = idx / 5, c = idx % 5;
    if (row >= M) return;
    float acc = 0.f;
#pragma unroll 8
    for (int k = 0; k < 128; k++) acc += X[row * 128 + k] * W[k * 5 + c];
    Y[row * 5 + c] = acc;
}

// ---------------- CSR aggregation, dim 128, bf16 gather: one wave per node ----------------
__global__ __launch_bounds__(256) void agg128_bf16(const uint* __restrict__ hb,
                                                   const int* __restrict__ rowptr,
                                                   const int* __restrict__ col,
                                                   const float* __restrict__ dinv,
                                                   const float* __restrict__ bias,
                                                   float* __restrict__ out, int N, int do_relu) {
    int wave = threadIdx.x >> 6;
    int lane = threadIdx.x & 63;
    int node = blockIdx.x * 4 + wave;
    if (node >= N) return;
    int beg = rowptr[node], end = rowptr[node + 1];
    float ax = 0.f, ay = 0.f;
    int j = beg;
    int e4 = beg + ((end - beg) & ~3);
    for (; j < e4; j += 4) {
        int s0 = col[j], s1 = col[j + 1], s2 = col[j + 2], s3 = col[j + 3];
        float w0 = dinv[s0], w1 = dinv[s1], w2 = dinv[s2], w3 = dinv[s3];
        uint v0 = hb[s0 * 64 + lane];
        uint v1 = hb[s1 * 64 + lane];
        uint v2 = hb[s2 * 64 + lane];
        uint v3 = hb[s3 * 64 + lane];
        ax = fmaf(__uint_as_float(v0 << 16), w0, ax);
        ay = fmaf(__uint_as_float(v0 & 0xFFFF0000u), w0, ay);
        ax = fmaf(__uint_as_float(v1 << 16), w1, ax);
        ay = fmaf(__uint_as_float(v1 & 0xFFFF0000u), w1, ay);
        ax = fmaf(__uint_as_float(v2 << 16), w2, ax);
        ay = fmaf(__uint_as_float(v2 & 0xFFFF0000u), w2, ay);
        ax = fmaf(__uint_as_float(v3 << 16), w3, ax);
        ay = fmaf(__uint_as_float(v3 & 0xFFFF0000u), w3, ay);
    }
    for (; j < end; ++j) {
        int s = col[j];
        float w = dinv[s];
        uint v = hb[s * 64 + lane];
        ax = fmaf(__uint_as_float(v << 16), w, ax);
        ay = fmaf(__uint_as_float(v & 0xFFFF0000u), w, ay);
    }
    float di = dinv[node];
    uint vs = hb[node * 64 + lane];
    float sx = __uint_as_float(vs << 16);
    float sy = __uint_as_float(vs & 0xFFFF0000u);
    float2 bb = reinterpret_cast<const float2*>(bias)[lane];
    float ox = ax * di + sx * di * di + bb.x;
    float oy = ay * di + sy * di * di + bb.y;
    if (do_relu) {
        ox = fmaxf(ox, 0.f);
        oy = fmaxf(oy, 0.f);
    }
    reinterpret_cast<float2*>(out)[node * 64 + lane] = make_float2(ox, oy);
}

// ---------------- CSR aggregation, dim 5: one thread per node ----------------
__global__ void agg5(const float* __restrict__ h, const int* __restrict__ rowptr,
                     const int* __restrict__ col, const float* __restrict__ dinv,
                     const float* __restrict__ b3, float* __restrict__ out, int N) {
    int node = blockIdx.x * 256 + threadIdx.x;
    if (node >= N) return;
    float acc[5] = {0.f, 0.f, 0.f, 0.f, 0.f};
    int beg = rowptr[node], end = rowptr[node + 1];
    for (int j = beg; j < end; ++j) {
        int s = col[j];
        float w = dinv[s];
#pragma unroll
        for (int f = 0; f < 5; f++) acc[f] += h[s * 5 + f] * w;
    }
    float di = dinv[node];
#pragma unroll
    for (int f = 0; f < 5; f++)
        out[node * 5 + f] = acc[f] * di + h[node * 5 + f] * di * di + b3[f];
}

static inline size_t align512(size_t x) { return (x + 511) & ~(size_t)511; }

extern "C" void kernel_launch(void* const* d_in, const int* in_sizes, int n_in,
                              void* d_out, int out_size, void* d_ws, size_t ws_size,
                              hipStream_t stream) {
    const float* x  = (const float*)d_in[0];
    const int* ei   = (const int*)d_in[1];
    const float* W1 = (const float*)d_in[2];
    const float* b1 = (const float*)d_in[3];
    const float* W2 = (const float*)d_in[4];
    const float* b2 = (const float*)d_in[5];
    const float* W3 = (const float*)d_in[6];
    const float* b3 = (const float*)d_in[7];
    const int* src = ei;
    const int* dst = ei + NE;

    char* ws = (char*)d_ws;
    size_t off = 0;
    int* cnt = (int*)(ws + off);        off += align512((size_t)NN * 4);
    int* rowptr = (int*)(ws + off);     off += align512((size_t)(NN + 1) * 4);
    float* dinv = (float*)(ws + off);   off += align512((size_t)NN * 4);
    int* bsum = (int*)(ws + off);       off += align512((size_t)128 * 4);
    int* ghist = (int*)(ws + off);      off += align512((size_t)GH * 4);
    int* col = (int*)(ws + off);        off += align512((size_t)NE * 4);
    uint* hb = (uint*)(ws + off);       off += align512((size_t)NN * 64 * 4);   // bf16 h (packed)
    float* bufF = (float*)(ws + off);   off += align512((size_t)NN * 128 * 4);  // fp32 agg out
    float* bufC = (float*)(ws + off);   off += align512((size_t)NN * 5 * 4);
    uint* binned = (uint*)bufF;  // alias: binned records only live before bufF's first use
    (void)ws_size;

    // ---- build CSR (by dst) + dinv, bucket-sorted for write locality ----
    hist_bkt<<<BIN_BLOCKS, 256, 0, stream>>>(dst, ghist);
    {
        int nb = (GH + SCAN_CHUNK - 1) / SCAN_CHUNK;  // 98
        scan_p1<<<nb, 256, 0, stream>>>(ghist, bsum, GH);
        scan_p2<<<1, 128, 0, stream>>>(bsum, nb);
        scan_p3_plain<<<nb, 256, 0, stream>>>(ghist, bsum, GH);
    }
    bin_edges<<<BIN_BLOCKS, 256, 0, stream>>>(src, dst, ghist, binned);
    bucket_count<<<NBKT, 256, 0, stream>>>(binned, ghist, cnt);
    {
        int nb = (NN + SCAN_CHUNK - 1) / SCAN_CHUNK;  // 98
        scan_p1<<<nb, 256, 0, stream>>>(cnt, bsum, NN);
        scan_p2<<<1, 128, 0, stream>>>(bsum, nb);
        scan_p3_deg<<<nb, 256, 0, stream>>>(cnt, bsum, rowptr, dinv, NN);
    }
    csr_fill<<<NBKT, 256, 0, stream>>>(binned, ghist, rowptr, col);

    int gemm_blocks = (NN + 63) / 64;
    // ---- layer 1 ----
    gemm_n128_bf16out<384><<<gemm_blocks, 256, 0, stream>>>(x, W1, hb, NN);
    agg128_bf16<<<(NN + 3) / 4, 256, 0, stream>>>(hb, rowptr, col, dinv, b1, bufF, NN, 1);
    // ---- layer 2 ----
    gemm_n128_bf16out<128><<<gemm_blocks, 256, 0, stream>>>(bufF, W2, hb, NN);
    agg128_bf16<<<(NN + 3) / 4, 256, 0, stream>>>(hb, rowptr, col, dinv, b2, bufF, NN, 1);
    // ---- layer 3 ----
    gemm_n5<<<((NN * 5) + 255) / 256, 256, 0, stream>>>(bufF, W3, bufC, NN);
    agg5<<<(NN + 255) / 256, 256, 0, stream>>>(bufC, rowptr, col, dinv, b3, (float*)d_out, NN);
}

// Round 5
// 549.079 us; speedup vs baseline: 2.5646x; 1.2039x over previous
//
#include <hip/hip_runtime.h>

#define NN 100000
#define NE 3200000
#define SCAN_CHUNK 1024

// bucket sort params
#define BSH 8
#define BKT_NODES 256                       // 1 << BSH
#define NBKT ((NN + BKT_NODES - 1) / BKT_NODES)   // 391
#define BIN_BLOCKS 256
#define EPB ((NE + BIN_BLOCKS - 1) / BIN_BLOCKS)  // 12500
#define GH (NBKT * BIN_BLOCKS)                    // 100096

typedef unsigned int uint;
typedef unsigned short ushort;
typedef __attribute__((ext_vector_type(8))) short short8;
typedef __attribute__((ext_vector_type(4))) float f32x4;

// round fp32 -> bf16 (RNE), return upper 16 bits
__device__ inline ushort bf16rne(float x) {
    uint u = __float_as_uint(x);
    u += 0x7FFFu + ((u >> 16) & 1u);
    return (ushort)(u >> 16);
}
// split x into hi bf16 + lo bf16 (x ~= hi + lo)
__device__ inline void split2(float x, ushort& h, ushort& l) {
    h = bf16rne(x);
    float hf = __uint_as_float((uint)h << 16);
    l = bf16rne(x - hf);
}
// pack two fp32 -> two bf16 (RNE) in one uint (a = low, b = high)
__device__ inline uint bf16pair(float a, float b) {
    uint ua = __float_as_uint(a);
    uint ub = __float_as_uint(b);
    ua += 0x7FFFu + ((ua >> 16) & 1u);
    ub += 0x7FFFu + ((ub >> 16) & 1u);
    return (ua >> 16) | (ub & 0xFFFF0000u);
}

// ---------------- bucket histogram (per binning-block, bucket-major out) ----------------
__global__ __launch_bounds__(256) void hist_bkt(const int* __restrict__ dst,
                                                int* __restrict__ ghist) {
    __shared__ int h[NBKT];
    int t = threadIdx.x;
    for (int i = t; i < NBKT; i += 256) h[i] = 0;
    __syncthreads();
    int beg = blockIdx.x * EPB;
    int end = beg + EPB; if (end > NE) end = NE;
    for (int e = beg + t; e < end; e += 256)
        atomicAdd(&h[dst[e] >> BSH], 1);
    __syncthreads();
    for (int i = t; i < NBKT; i += 256)
        ghist[i * BIN_BLOCKS + blockIdx.x] = h[i];
}

// ---------------- hierarchical scan: phase 1 (per-block sums) ----------------
__global__ __launch_bounds__(256) void scan_p1(const int* __restrict__ cnt,
                                               int* __restrict__ bsum, int N) {
    int t = threadIdx.x;
    int base = blockIdx.x * SCAN_CHUNK + t * 4;
    int s = 0;
#pragma unroll
    for (int q = 0; q < 4; q++) {
        int i = base + q;
        if (i < N) s += cnt[i];
    }
    __shared__ int red[4];
#pragma unroll
    for (int off = 32; off; off >>= 1) s += __shfl_down(s, off, 64);
    if ((t & 63) == 0) red[t >> 6] = s;
    __syncthreads();
    if (t == 0) bsum[blockIdx.x] = red[0] + red[1] + red[2] + red[3];
}

// ---------------- phase 2: exclusive scan of block sums ----------------
__global__ void scan_p2(int* __restrict__ bsum, int nb) {
    __shared__ int s[128];
    int t = threadIdx.x;
    int v = (t < nb) ? bsum[t] : 0;
    s[t] = v;
    __syncthreads();
    for (int off = 1; off < 128; off <<= 1) {
        int x = s[t];
        int add = (t >= off) ? s[t - off] : 0;
        __syncthreads();
        s[t] = x + add;
        __syncthreads();
    }
    if (t < nb) bsum[t] = s[t] - v;  // exclusive
}

// ---------------- phase 3a: in-place exclusive scan ----------------
__global__ __launch_bounds__(256) void scan_p3_plain(int* __restrict__ data,
                                                     const int* __restrict__ bsum, int N) {
    __shared__ int ts[256];
    int t = threadIdx.x;
    int base = blockIdx.x * SCAN_CHUNK + t * 4;
    int c[4];
    int s = 0;
#pragma unroll
    for (int q = 0; q < 4; q++) {
        int i = base + q;
        c[q] = (i < N) ? data[i] : 0;
        s += c[q];
    }
    ts[t] = s;
    __syncthreads();
    for (int off = 1; off < 256; off <<= 1) {
        int x = ts[t];
        int add = (t >= off) ? ts[t - off] : 0;
        __syncthreads();
        ts[t] = x + add;
        __syncthreads();
    }
    int run = bsum[blockIdx.x] + ts[t] - s;
#pragma unroll
    for (int q = 0; q < 4; q++) {
        int i = base + q;
        if (i < N) { data[i] = run; run += c[q]; }
    }
}

// ---------------- phase 3b: scan + rowptr + dinv ----------------
__global__ __launch_bounds__(256) void scan_p3_deg(const int* __restrict__ cnt,
                                                   const int* __restrict__ bsum,
                                                   int* __restrict__ rowptr,
                                                   float* __restrict__ dinv, int N) {
    __shared__ int ts[256];
    int t = threadIdx.x;
    int base = blockIdx.x * SCAN_CHUNK + t * 4;
    int c[4];
    int s = 0;
#pragma unroll
    for (int q = 0; q < 4; q++) {
        int i = base + q;
        c[q] = (i < N) ? cnt[i] : 0;
        s += c[q];
    }
    ts[t] = s;
    __syncthreads();
    for (int off = 1; off < 256; off <<= 1) {
        int x = ts[t];
        int add = (t >= off) ? ts[t - off] : 0;
        __syncthreads();
        ts[t] = x + add;
        __syncthreads();
    }
    int run = bsum[blockIdx.x] + ts[t] - s;
#pragma unroll
    for (int q = 0; q < 4; q++) {
        int i = base + q;
        if (i < N) {
            rowptr[i] = run;
            dinv[i] = 1.0f / sqrtf((float)(c[q] + 1));  // +1 self-loop
            run += c[q];
        }
    }
    if (base < N && N <= base + 4) rowptr[N] = run;
}

// ---------------- bin edges into bucket-segmented records ----------------
__global__ __launch_bounds__(256) void bin_edges(const int* __restrict__ src,
                                                 const int* __restrict__ dst,
                                                 const int* __restrict__ ghist,
                                                 uint* __restrict__ binned) {
    __shared__ int cur[NBKT];
    int t = threadIdx.x;
    for (int i = t; i < NBKT; i += 256) cur[i] = ghist[i * BIN_BLOCKS + blockIdx.x];
    __syncthreads();
    int beg = blockIdx.x * EPB;
    int end = beg + EPB; if (end > NE) end = NE;
    for (int e = beg + t; e < end; e += 256) {
        int d = dst[e];
        int b = d >> BSH;
        int p = atomicAdd(&cur[b], 1);
        binned[p] = ((uint)src[e] << BSH) | (uint)(d & (BKT_NODES - 1));
    }
}

// ---------------- per-bucket node degree count ----------------
__global__ __launch_bounds__(256) void bucket_count(const uint* __restrict__ binned,
                                                    const int* __restrict__ ghist,
                                                    int* __restrict__ cnt) {
    __shared__ int c[BKT_NODES];
    int t = threadIdx.x;
    int bkt = blockIdx.x;
    for (int i = t; i < BKT_NODES; i += 256) c[i] = 0;
    __syncthreads();
    int beg = ghist[bkt * BIN_BLOCKS];
    int end = (bkt == NBKT - 1) ? NE : ghist[(bkt + 1) * BIN_BLOCKS];
    for (int j = beg + t; j < end; j += 256)
        atomicAdd(&c[binned[j] & (BKT_NODES - 1)], 1);
    __syncthreads();
    int base = bkt * BKT_NODES;
    int nb = NN - base; if (nb > BKT_NODES) nb = BKT_NODES;
    for (int i = t; i < nb; i += 256) cnt[base + i] = c[i];
}

// ---------------- per-bucket CSR fill ----------------
__global__ __launch_bounds__(256) void csr_fill(const uint* __restrict__ binned,
                                                const int* __restrict__ ghist,
                                                const int* __restrict__ rowptr,
                                                int* __restrict__ col) {
    __shared__ int fill[BKT_NODES];
    int t = threadIdx.x;
    int bkt = blockIdx.x;
    for (int i = t; i < BKT_NODES; i += 256) fill[i] = 0;
    __syncthreads();
    int beg = ghist[bkt * BIN_BLOCKS];
    int end = (bkt == NBKT - 1) ? NE : ghist[(bkt + 1) * BIN_BLOCKS];
    int base = bkt * BKT_NODES;
    for (int j = beg + t; j < end; j += 256) {
        uint r = binned[j];
        int dl = r & (BKT_NODES - 1);
        int p = rowptr[base + dl] + atomicAdd(&fill[dl], 1);
        col[p] = (int)(r >> BSH);
    }
}

// ---------------- W transpose + bf16 hi/lo split: W[K][128] -> Wt[128][K] ----------------
template <int K>
__global__ __launch_bounds__(256) void wsplit(const float* __restrict__ W,
                                              ushort* __restrict__ Wth,
                                              ushort* __restrict__ Wtl) {
    __shared__ float tile[32][128];
    int t = threadIdx.x;
    int kb = blockIdx.x;
    {
        int k = t >> 3, cq = t & 7;
#pragma unroll
        for (int q = 0; q < 4; q++) {
            float4 v = *(const float4*)&W[(size_t)(kb * 32 + k) * 128 + cq * 16 + q * 4];
            *(float4*)&tile[k][cq * 16 + q * 4] = v;
        }
    }
    __syncthreads();
    {
        int c = t >> 1, g = t & 1;
        ushort hs[16], ls[16];
#pragma unroll
        for (int i = 0; i < 16; i++) split2(tile[g * 16 + i][c], hs[i], ls[i]);
        uint h[8], lo[8];
#pragma unroll
        for (int i = 0; i < 8; i++) {
            h[i] = (uint)hs[2 * i] | ((uint)hs[2 * i + 1] << 16);
            lo[i] = (uint)ls[2 * i] | ((uint)ls[2 * i + 1] << 16);
        }
        size_t o = (size_t)c * K + kb * 32 + g * 16;
        *(uint4*)&Wth[o] = make_uint4(h[0], h[1], h[2], h[3]);
        *(uint4*)&Wth[o + 8] = make_uint4(h[4], h[5], h[6], h[7]);
        *(uint4*)&Wtl[o] = make_uint4(lo[0], lo[1], lo[2], lo[3]);
        *(uint4*)&Wtl[o + 8] = make_uint4(lo[4], lo[5], lo[6], lo[7]);
    }
}

// ---------------- MFMA GEMM: X[M][K] fp32 @ Wt[128][K] (bf16 hi/lo) -> hb packed bf16 ----------------
// 64 rows x 128 cols per block, 4 waves, bf16x3 split for ~fp32 accuracy.
template <int K>
__global__ __launch_bounds__(256) void mfma_gemm(const float* __restrict__ X,
                                                 const ushort* __restrict__ Wth,
                                                 const ushort* __restrict__ Wtl,
                                                 uint* __restrict__ Y, int M) {
    __shared__ char smem[24 * 1024];
    char* aHi = smem;             // 4 KB: A hi chunks
    char* aLo = smem + 4096;      // 4 KB
    char* bHi = smem + 8192;      // 8 KB: B hi chunks
    char* bLo = smem + 16384;     // 8 KB
    int tid = threadIdx.x;
    int w = tid >> 6, l = tid & 63;
    int rowBase = blockIdx.x * 64;

    f32x4 acc[8];
#pragma unroll
    for (int n = 0; n < 8; n++) acc[n] = (f32x4){0.f, 0.f, 0.f, 0.f};

    int sRow = tid >> 2, sKg = tid & 3;  // A staging: row 0..63, k-group 0..3
    int gRowA = rowBase + sRow;
    int fKg = l >> 4;                    // fragment k-group
    int aOff = fKg * 1024 + ((16 * w + (l & 15)) ^ fKg) * 16;

    for (int kt = 0; kt < K; kt += 32) {
        // ---- stage A (64 x 32 fp32 -> hi/lo bf16 chunks) ----
        {
            float v[8];
            if (gRowA < M) {
                float4 p0 = *(const float4*)&X[(size_t)gRowA * K + kt + sKg * 8];
                float4 p1 = *(const float4*)&X[(size_t)gRowA * K + kt + sKg * 8 + 4];
                v[0] = p0.x; v[1] = p0.y; v[2] = p0.z; v[3] = p0.w;
                v[4] = p1.x; v[5] = p1.y; v[6] = p1.z; v[7] = p1.w;
            } else {
#pragma unroll
                for (int i = 0; i < 8; i++) v[i] = 0.f;
            }
            uint hh[4], hl[4];
#pragma unroll
            for (int i = 0; i < 4; i++) {
                ushort h0, l0, h1, l1;
                split2(v[2 * i], h0, l0);
                split2(v[2 * i + 1], h1, l1);
                hh[i] = (uint)h0 | ((uint)h1 << 16);
                hl[i] = (uint)l0 | ((uint)l1 << 16);
            }
            int wa = sKg * 1024 + ((sRow ^ sKg) * 16);
            *(uint4*)(aHi + wa) = make_uint4(hh[0], hh[1], hh[2], hh[3]);
            *(uint4*)(aLo + wa) = make_uint4(hl[0], hl[1], hl[2], hl[3]);
        }
        // ---- stage B (128 cols x 32 k, from pre-split Wt) ----
#pragma unroll
        for (int i = 0; i < 2; i++) {
            int ci = tid + i * 256;
            int colb = ci >> 2, kg = ci & 3;
            uint4 vh = *(const uint4*)&Wth[(size_t)colb * K + kt + kg * 8];
            uint4 vl = *(const uint4*)&Wtl[(size_t)colb * K + kt + kg * 8];
            int wb = kg * 2048 + ((colb ^ kg) * 16);
            *(uint4*)(bHi + wb) = vh;
            *(uint4*)(bLo + wb) = vl;
        }
        __syncthreads();
        short8 ah = *(const short8*)(aHi + aOff);
        short8 al = *(const short8*)(aLo + aOff);
#pragma unroll
        for (int n = 0; n < 8; n++) {
            int bOff = fKg * 2048 + ((16 * n + (l & 15)) ^ fKg) * 16;
            short8 bh = *(const short8*)(bHi + bOff);
            short8 bl = *(const short8*)(bLo + bOff);
            acc[n] = __builtin_amdgcn_mfma_f32_16x16x32_bf16(ah, bh, acc[n], 0, 0, 0);
            acc[n] = __builtin_amdgcn_mfma_f32_16x16x32_bf16(ah, bl, acc[n], 0, 0, 0);
            acc[n] = __builtin_amdgcn_mfma_f32_16x16x32_bf16(al, bh, acc[n], 0, 0, 0);
        }
        __syncthreads();
    }
    // ---- epilogue: D[row=(l>>4)*4+r][col=16n+(l&15)] -> packed bf16 pairs ----
#pragma unroll
    for (int n = 0; n < 8; n++) {
#pragma unroll
        for (int r = 0; r < 4; r++) {
            float val = acc[n][r];
            float p = __shfl_xor(val, 1, 64);
            int row = rowBase + 16 * w + (l >> 4) * 4 + r;
            if (!(l & 1) && row < M)
                Y[(size_t)row * 64 + 8 * n + ((l & 15) >> 1)] = bf16pair(val, p);
        }
    }
}

// ---------------- small GEMM, N=5, K=128 (fp32 in/out) ----------------
__global__ void gemm_n5(const float* __restrict__ X, const float* __restrict__ W,
                        float* __restrict__ Y, int M) {
    int idx = blockIdx.x * 256 + threadIdx.x;
    int row = idx / 5, c = idx % 5;
    if (row >= M) return;
    float acc = 0.f;
#pragma unroll 8
    for (int k = 0; k < 128; k++) acc += X[row * 128 + k] * W[k * 5 + c];
    Y[row * 5 + c] = acc;
}

// ---------------- CSR aggregation, dim 128, bf16 gather: one wave per node ----------------
__global__ __launch_bounds__(256) void agg128_bf16(const uint* __restrict__ hb,
                                                   const int* __restrict__ rowptr,
                                                   const int* __restrict__ col,
                                                   const float* __restrict__ dinv,
                                                   const float* __restrict__ bias,
                                                   float* __restrict__ out, int N, int do_relu) {
    int wave = threadIdx.x >> 6;
    int lane = threadIdx.x & 63;
    int node = blockIdx.x * 4 + wave;
    if (node >= N) return;
    int beg = rowptr[node], end = rowptr[node + 1];
    float ax = 0.f, ay = 0.f;
    int j = beg;
    int e4 = beg + ((end - beg) & ~3);
    for (; j < e4; j += 4) {
        int s0 = col[j], s1 = col[j + 1], s2 = col[j + 2], s3 = col[j + 3];
        float w0 = dinv[s0], w1 = dinv[s1], w2 = dinv[s2], w3 = dinv[s3];
        uint v0 = hb[s0 * 64 + lane];
        uint v1 = hb[s1 * 64 + lane];
        uint v2 = hb[s2 * 64 + lane];
        uint v3 = hb[s3 * 64 + lane];
        ax = fmaf(__uint_as_float(v0 << 16), w0, ax);
        ay = fmaf(__uint_as_float(v0 & 0xFFFF0000u), w0, ay);
        ax = fmaf(__uint_as_float(v1 << 16), w1, ax);
        ay = fmaf(__uint_as_float(v1 & 0xFFFF0000u), w1, ay);
        ax = fmaf(__uint_as_float(v2 << 16), w2, ax);
        ay = fmaf(__uint_as_float(v2 & 0xFFFF0000u), w2, ay);
        ax = fmaf(__uint_as_float(v3 << 16), w3, ax);
        ay = fmaf(__uint_as_float(v3 & 0xFFFF0000u), w3, ay);
    }
    for (; j < end; ++j) {
        int s = col[j];
        float w = dinv[s];
        uint v = hb[s * 64 + lane];
        ax = fmaf(__uint_as_float(v << 16), w, ax);
        ay = fmaf(__uint_as_float(v & 0xFFFF0000u), w, ay);
    }
    float di = dinv[node];
    uint vs = hb[node * 64 + lane];
    float sx = __uint_as_float(vs << 16);
    float sy = __uint_as_float(vs & 0xFFFF0000u);
    float2 bb = reinterpret_cast<const float2*>(bias)[lane];
    float ox = ax * di + sx * di * di + bb.x;
    float oy = ay * di + sy * di * di + bb.y;
    if (do_relu) {
        ox = fmaxf(ox, 0.f);
        oy = fmaxf(oy, 0.f);
    }
    reinterpret_cast<float2*>(out)[node * 64 + lane] = make_float2(ox, oy);
}

// ---------------- CSR aggregation, dim 5: one thread per node ----------------
__global__ void agg5(const float* __restrict__ h, const int* __restrict__ rowptr,
                     const int* __restrict__ col, const float* __restrict__ dinv,
                     const float* __restrict__ b3, float* __restrict__ out, int N) {
    int node = blockIdx.x * 256 + threadIdx.x;
    if (node >= N) return;
    float acc[5] = {0.f, 0.f, 0.f, 0.f, 0.f};
    int beg = rowptr[node], end = rowptr[node + 1];
    for (int j = beg; j < end; ++j) {
        int s = col[j];
        float w = dinv[s];
#pragma unroll
        for (int f = 0; f < 5; f++) acc[f] += h[s * 5 + f] * w;
    }
    float di = dinv[node];
#pragma unroll
    for (int f = 0; f < 5; f++)
        out[node * 5 + f] = acc[f] * di + h[node * 5 + f] * di * di + b3[f];
}

static inline size_t align512(size_t x) { return (x + 511) & ~(size_t)511; }

extern "C" void kernel_launch(void* const* d_in, const int* in_sizes, int n_in,
                              void* d_out, int out_size, void* d_ws, size_t ws_size,
                              hipStream_t stream) {
    const float* x  = (const float*)d_in[0];
    const int* ei   = (const int*)d_in[1];
    const float* W1 = (const float*)d_in[2];
    const float* b1 = (const float*)d_in[3];
    const float* W2 = (const float*)d_in[4];
    const float* b2 = (const float*)d_in[5];
    const float* W3 = (const float*)d_in[6];
    const float* b3 = (const float*)d_in[7];
    const int* src = ei;
    const int* dst = ei + NE;

    char* ws = (char*)d_ws;
    size_t off = 0;
    int* cnt = (int*)(ws + off);        off += align512((size_t)NN * 4);
    int* rowptr = (int*)(ws + off);     off += align512((size_t)(NN + 1) * 4);
    float* dinv = (float*)(ws + off);   off += align512((size_t)NN * 4);
    int* bsum = (int*)(ws + off);       off += align512((size_t)128 * 4);
    int* ghist = (int*)(ws + off);      off += align512((size_t)GH * 4);
    ushort* wt1h = (ushort*)(ws + off); off += align512((size_t)128 * 384 * 2);
    ushort* wt1l = (ushort*)(ws + off); off += align512((size_t)128 * 384 * 2);
    ushort* wt2h = (ushort*)(ws + off); off += align512((size_t)128 * 128 * 2);
    ushort* wt2l = (ushort*)(ws + off); off += align512((size_t)128 * 128 * 2);
    int* col = (int*)(ws + off);        off += align512((size_t)NE * 4);
    uint* hb = (uint*)(ws + off);       off += align512((size_t)NN * 64 * 4);   // bf16 h (packed)
    float* bufF = (float*)(ws + off);   off += align512((size_t)NN * 128 * 4);  // fp32 agg out
    float* bufC = (float*)(ws + off);   off += align512((size_t)NN * 5 * 4);
    uint* binned = (uint*)bufF;  // alias: binned records only live before bufF's first use
    (void)ws_size;

    // ---- W transpose + hi/lo split (independent of CSR chain) ----
    wsplit<384><<<12, 256, 0, stream>>>(W1, wt1h, wt1l);
    wsplit<128><<<4, 256, 0, stream>>>(W2, wt2h, wt2l);

    // ---- build CSR (by dst) + dinv, bucket-sorted for write locality ----
    hist_bkt<<<BIN_BLOCKS, 256, 0, stream>>>(dst, ghist);
    {
        int nb = (GH + SCAN_CHUNK - 1) / SCAN_CHUNK;  // 98
        scan_p1<<<nb, 256, 0, stream>>>(ghist, bsum, GH);
        scan_p2<<<1, 128, 0, stream>>>(bsum, nb);
        scan_p3_plain<<<nb, 256, 0, stream>>>(ghist, bsum, GH);
    }
    bin_edges<<<BIN_BLOCKS, 256, 0, stream>>>(src, dst, ghist, binned);
    bucket_count<<<NBKT, 256, 0, stream>>>(binned, ghist, cnt);
    {
        int nb = (NN + SCAN_CHUNK - 1) / SCAN_CHUNK;  // 98
        scan_p1<<<nb, 256, 0, stream>>>(cnt, bsum, NN);
        scan_p2<<<1, 128, 0, stream>>>(bsum, nb);
        scan_p3_deg<<<nb, 256, 0, stream>>>(cnt, bsum, rowptr, dinv, NN);
    }
    csr_fill<<<NBKT, 256, 0, stream>>>(binned, ghist, rowptr, col);

    int gemm_blocks = (NN + 63) / 64;  // 1563
    // ---- layer 1 ----
    mfma_gemm<384><<<gemm_blocks, 256, 0, stream>>>(x, wt1h, wt1l, hb, NN);
    agg128_bf16<<<(NN + 3) / 4, 256, 0, stream>>>(hb, rowptr, col, dinv, b1, bufF, NN, 1);
    // ---- layer 2 ----
    mfma_gemm<128><<<gemm_blocks, 256, 0, stream>>>(bufF, wt2h, wt2l, hb, NN);
    agg128_bf16<<<(NN + 3) / 4, 256, 0, stream>>>(hb, rowptr, col, dinv, b2, bufF, NN, 1);
    // ---- layer 3 ----
    gemm_n5<<<((NN * 5) + 255) / 256, 256, 0, stream>>>(bufF, W3, bufC, NN);
    agg5<<<(NN + 255) / 256, 256, 0, stream>>>(bufC, rowptr, col, dinv, b3, (float*)d_out, NN);
}

// Round 6
// 495.401 us; speedup vs baseline: 2.8425x; 1.1084x over previous
//
#include <hip/hip_runtime.h>

#define NN 100000
#define NE 3200000
#define SCAN_CHUNK 1024

// bucket sort params
#define BSH 8
#define BKT_NODES 256                       // 1 << BSH
#define NBKT ((NN + BKT_NODES - 1) / BKT_NODES)   // 391
#define BIN_BLOCKS 256
#define EPB ((NE + BIN_BLOCKS - 1) / BIN_BLOCKS)  // 12500
#define GH (NBKT * BIN_BLOCKS)                    // 100096

typedef unsigned int uint;
typedef unsigned short ushort;
typedef __attribute__((ext_vector_type(8))) short short8;
typedef __attribute__((ext_vector_type(4))) float f32x4;

// round fp32 -> bf16 (RNE), return upper 16 bits
__device__ inline ushort bf16rne(float x) {
    uint u = __float_as_uint(x);
    u += 0x7FFFu + ((u >> 16) & 1u);
    return (ushort)(u >> 16);
}
// split x into hi bf16 + lo bf16 (x ~= hi + lo)
__device__ inline void split2(float x, ushort& h, ushort& l) {
    h = bf16rne(x);
    float hf = __uint_as_float((uint)h << 16);
    l = bf16rne(x - hf);
}
// pack two fp32 -> two bf16 (RNE) in one uint (a = low, b = high)
__device__ inline uint bf16pair(float a, float b) {
    uint ua = __float_as_uint(a);
    uint ub = __float_as_uint(b);
    ua += 0x7FFFu + ((ua >> 16) & 1u);
    ub += 0x7FFFu + ((ub >> 16) & 1u);
    return (ua >> 16) | (ub & 0xFFFF0000u);
}
__device__ inline float bflo(uint u) { return __uint_as_float(u << 16); }
__device__ inline float bfhi(uint u) { return __uint_as_float(u & 0xFFFF0000u); }

// ---------------- bucket histogram ----------------
__global__ __launch_bounds__(256) void hist_bkt(const int* __restrict__ dst,
                                                int* __restrict__ ghist) {
    __shared__ int h[NBKT];
    int t = threadIdx.x;
    for (int i = t; i < NBKT; i += 256) h[i] = 0;
    __syncthreads();
    int beg = blockIdx.x * EPB;
    int end = beg + EPB; if (end > NE) end = NE;
    for (int e = beg + t; e < end; e += 256)
        atomicAdd(&h[dst[e] >> BSH], 1);
    __syncthreads();
    for (int i = t; i < NBKT; i += 256)
        ghist[i * BIN_BLOCKS + blockIdx.x] = h[i];
}

// ---------------- hierarchical scan: phase 1 ----------------
__global__ __launch_bounds__(256) void scan_p1(const int* __restrict__ cnt,
                                               int* __restrict__ bsum, int N) {
    int t = threadIdx.x;
    int base = blockIdx.x * SCAN_CHUNK + t * 4;
    int s = 0;
#pragma unroll
    for (int q = 0; q < 4; q++) {
        int i = base + q;
        if (i < N) s += cnt[i];
    }
    __shared__ int red[4];
#pragma unroll
    for (int off = 32; off; off >>= 1) s += __shfl_down(s, off, 64);
    if ((t & 63) == 0) red[t >> 6] = s;
    __syncthreads();
    if (t == 0) bsum[blockIdx.x] = red[0] + red[1] + red[2] + red[3];
}

// ---------------- phase 2 ----------------
__global__ void scan_p2(int* __restrict__ bsum, int nb) {
    __shared__ int s[128];
    int t = threadIdx.x;
    int v = (t < nb) ? bsum[t] : 0;
    s[t] = v;
    __syncthreads();
    for (int off = 1; off < 128; off <<= 1) {
        int x = s[t];
        int add = (t >= off) ? s[t - off] : 0;
        __syncthreads();
        s[t] = x + add;
        __syncthreads();
    }
    if (t < nb) bsum[t] = s[t] - v;  // exclusive
}

// ---------------- phase 3a: in-place exclusive scan ----------------
__global__ __launch_bounds__(256) void scan_p3_plain(int* __restrict__ data,
                                                     const int* __restrict__ bsum, int N) {
    __shared__ int ts[256];
    int t = threadIdx.x;
    int base = blockIdx.x * SCAN_CHUNK + t * 4;
    int c[4];
    int s = 0;
#pragma unroll
    for (int q = 0; q < 4; q++) {
        int i = base + q;
        c[q] = (i < N) ? data[i] : 0;
        s += c[q];
    }
    ts[t] = s;
    __syncthreads();
    for (int off = 1; off < 256; off <<= 1) {
        int x = ts[t];
        int add = (t >= off) ? ts[t - off] : 0;
        __syncthreads();
        ts[t] = x + add;
        __syncthreads();
    }
    int run = bsum[blockIdx.x] + ts[t] - s;
#pragma unroll
    for (int q = 0; q < 4; q++) {
        int i = base + q;
        if (i < N) { data[i] = run; run += c[q]; }
    }
}

// ---------------- phase 3b: scan + rowptr + dinv ----------------
__global__ __launch_bounds__(256) void scan_p3_deg(const int* __restrict__ cnt,
                                                   const int* __restrict__ bsum,
                                                   int* __restrict__ rowptr,
                                                   float* __restrict__ dinv, int N) {
    __shared__ int ts[256];
    int t = threadIdx.x;
    int base = blockIdx.x * SCAN_CHUNK + t * 4;
    int c[4];
    int s = 0;
#pragma unroll
    for (int q = 0; q < 4; q++) {
        int i = base + q;
        c[q] = (i < N) ? cnt[i] : 0;
        s += c[q];
    }
    ts[t] = s;
    __syncthreads();
    for (int off = 1; off < 256; off <<= 1) {
        int x = ts[t];
        int add = (t >= off) ? ts[t - off] : 0;
        __syncthreads();
        ts[t] = x + add;
        __syncthreads();
    }
    int run = bsum[blockIdx.x] + ts[t] - s;
#pragma unroll
    for (int q = 0; q < 4; q++) {
        int i = base + q;
        if (i < N) {
            rowptr[i] = run;
            dinv[i] = 1.0f / sqrtf((float)(c[q] + 1));  // +1 self-loop
            run += c[q];
        }
    }
    if (base < N && N <= base + 4) rowptr[N] = run;
}

// ---------------- bin edges into bucket-segmented records ----------------
__global__ __launch_bounds__(256) void bin_edges(const int* __restrict__ src,
                                                 const int* __restrict__ dst,
                                                 const int* __restrict__ ghist,
                                                 uint* __restrict__ binned) {
    __shared__ int cur[NBKT];
    int t = threadIdx.x;
    for (int i = t; i < NBKT; i += 256) cur[i] = ghist[i * BIN_BLOCKS + blockIdx.x];
    __syncthreads();
    int beg = blockIdx.x * EPB;
    int end = beg + EPB; if (end > NE) end = NE;
    for (int e = beg + t; e < end; e += 256) {
        int d = dst[e];
        int b = d >> BSH;
        int p = atomicAdd(&cur[b], 1);
        binned[p] = ((uint)src[e] << BSH) | (uint)(d & (BKT_NODES - 1));
    }
}

// ---------------- per-bucket node degree count ----------------
__global__ __launch_bounds__(256) void bucket_count(const uint* __restrict__ binned,
                                                    const int* __restrict__ ghist,
                                                    int* __restrict__ cnt) {
    __shared__ int c[BKT_NODES];
    int t = threadIdx.x;
    int bkt = blockIdx.x;
    for (int i = t; i < BKT_NODES; i += 256) c[i] = 0;
    __syncthreads();
    int beg = ghist[bkt * BIN_BLOCKS];
    int end = (bkt == NBKT - 1) ? NE : ghist[(bkt + 1) * BIN_BLOCKS];
    for (int j = beg + t; j < end; j += 256)
        atomicAdd(&c[binned[j] & (BKT_NODES - 1)], 1);
    __syncthreads();
    int base = bkt * BKT_NODES;
    int nb = NN - base; if (nb > BKT_NODES) nb = BKT_NODES;
    for (int i = t; i < nb; i += 256) cnt[base + i] = c[i];
}

// ---------------- per-bucket CSR fill ----------------
__global__ __launch_bounds__(256) void csr_fill(const uint* __restrict__ binned,
                                                const int* __restrict__ ghist,
                                                const int* __restrict__ rowptr,
                                                int* __restrict__ col) {
    __shared__ int fill[BKT_NODES];
    int t = threadIdx.x;
    int bkt = blockIdx.x;
    for (int i = t; i < BKT_NODES; i += 256) fill[i] = 0;
    __syncthreads();
    int beg = ghist[bkt * BIN_BLOCKS];
    int end = (bkt == NBKT - 1) ? NE : ghist[(bkt + 1) * BIN_BLOCKS];
    int base = bkt * BKT_NODES;
    for (int j = beg + t; j < end; j += 256) {
        uint r = binned[j];
        int dl = r & (BKT_NODES - 1);
        int p = rowptr[base + dl] + atomicAdd(&fill[dl], 1);
        col[p] = (int)(r >> BSH);
    }
}

// ---------------- W transpose + bf16 hi/lo split: W[K][128] -> Wt[128][K] ----------------
template <int K>
__global__ __launch_bounds__(256) void wsplit(const float* __restrict__ W,
                                              ushort* __restrict__ Wth,
                                              ushort* __restrict__ Wtl) {
    __shared__ float tile[32][128];
    int t = threadIdx.x;
    int kb = blockIdx.x;
    {
        int k = t >> 3, cq = t & 7;
#pragma unroll
        for (int q = 0; q < 4; q++) {
            float4 v = *(const float4*)&W[(size_t)(kb * 32 + k) * 128 + cq * 16 + q * 4];
            *(float4*)&tile[k][cq * 16 + q * 4] = v;
        }
    }
    __syncthreads();
    {
        int c = t >> 1, g = t & 1;
        ushort hs[16], ls[16];
#pragma unroll
        for (int i = 0; i < 16; i++) split2(tile[g * 16 + i][c], hs[i], ls[i]);
        uint h[8], lo[8];
#pragma unroll
        for (int i = 0; i < 8; i++) {
            h[i] = (uint)hs[2 * i] | ((uint)hs[2 * i + 1] << 16);
            lo[i] = (uint)ls[2 * i] | ((uint)ls[2 * i + 1] << 16);
        }
        size_t o = (size_t)c * K + kb * 32 + g * 16;
        *(uint4*)&Wth[o] = make_uint4(h[0], h[1], h[2], h[3]);
        *(uint4*)&Wth[o + 8] = make_uint4(h[4], h[5], h[6], h[7]);
        *(uint4*)&Wtl[o] = make_uint4(lo[0], lo[1], lo[2], lo[3]);
        *(uint4*)&Wtl[o + 8] = make_uint4(lo[4], lo[5], lo[6], lo[7]);
    }
}

// ---------------- MFMA GEMM: X @ Wt (bf16x3) -> hb packed bf16, PRE-SCALED by dinv[row] ----------------
template <int K>
__global__ __launch_bounds__(256) void mfma_gemm(const float* __restrict__ X,
                                                 const ushort* __restrict__ Wth,
                                                 const ushort* __restrict__ Wtl,
                                                 const float* __restrict__ dinv,
                                                 uint* __restrict__ Y, int M) {
    __shared__ char smem[24 * 1024];
    char* aHi = smem;
    char* aLo = smem + 4096;
    char* bHi = smem + 8192;
    char* bLo = smem + 16384;
    int tid = threadIdx.x;
    int w = tid >> 6, l = tid & 63;
    int rowBase = blockIdx.x * 64;

    f32x4 acc[8];
#pragma unroll
    for (int n = 0; n < 8; n++) acc[n] = (f32x4){0.f, 0.f, 0.f, 0.f};

    int sRow = tid >> 2, sKg = tid & 3;
    int gRowA = rowBase + sRow;
    int fKg = l >> 4;
    int aOff = fKg * 1024 + ((16 * w + (l & 15)) ^ fKg) * 16;

    for (int kt = 0; kt < K; kt += 32) {
        {
            float v[8];
            if (gRowA < M) {
                float4 p0 = *(const float4*)&X[(size_t)gRowA * K + kt + sKg * 8];
                float4 p1 = *(const float4*)&X[(size_t)gRowA * K + kt + sKg * 8 + 4];
                v[0] = p0.x; v[1] = p0.y; v[2] = p0.z; v[3] = p0.w;
                v[4] = p1.x; v[5] = p1.y; v[6] = p1.z; v[7] = p1.w;
            } else {
#pragma unroll
                for (int i = 0; i < 8; i++) v[i] = 0.f;
            }
            uint hh[4], hl[4];
#pragma unroll
            for (int i = 0; i < 4; i++) {
                ushort h0, l0, h1, l1;
                split2(v[2 * i], h0, l0);
                split2(v[2 * i + 1], h1, l1);
                hh[i] = (uint)h0 | ((uint)h1 << 16);
                hl[i] = (uint)l0 | ((uint)l1 << 16);
            }
            int wa = sKg * 1024 + ((sRow ^ sKg) * 16);
            *(uint4*)(aHi + wa) = make_uint4(hh[0], hh[1], hh[2], hh[3]);
            *(uint4*)(aLo + wa) = make_uint4(hl[0], hl[1], hl[2], hl[3]);
        }
#pragma unroll
        for (int i = 0; i < 2; i++) {
            int ci = tid + i * 256;
            int colb = ci >> 2, kg = ci & 3;
            uint4 vh = *(const uint4*)&Wth[(size_t)colb * K + kt + kg * 8];
            uint4 vl = *(const uint4*)&Wtl[(size_t)colb * K + kt + kg * 8];
            int wb = kg * 2048 + ((colb ^ kg) * 16);
            *(uint4*)(bHi + wb) = vh;
            *(uint4*)(bLo + wb) = vl;
        }
        __syncthreads();
        short8 ah = *(const short8*)(aHi + aOff);
        short8 al = *(const short8*)(aLo + aOff);
#pragma unroll
        for (int n = 0; n < 8; n++) {
            int bOff = fKg * 2048 + ((16 * n + (l & 15)) ^ fKg) * 16;
            short8 bh = *(const short8*)(bHi + bOff);
            short8 bl = *(const short8*)(bLo + bOff);
            acc[n] = __builtin_amdgcn_mfma_f32_16x16x32_bf16(ah, bh, acc[n], 0, 0, 0);
            acc[n] = __builtin_amdgcn_mfma_f32_16x16x32_bf16(ah, bl, acc[n], 0, 0, 0);
            acc[n] = __builtin_amdgcn_mfma_f32_16x16x32_bf16(al, bh, acc[n], 0, 0, 0);
        }
        __syncthreads();
    }
    // dinv scales for this thread's 4 rows
    float dscale[4];
#pragma unroll
    for (int r = 0; r < 4; r++) {
        int row = rowBase + 16 * w + (l >> 4) * 4 + r;
        dscale[r] = (row < M) ? dinv[row] : 0.f;
    }
    // epilogue: D[row][col] scaled -> packed bf16 pairs
#pragma unroll
    for (int n = 0; n < 8; n++) {
#pragma unroll
        for (int r = 0; r < 4; r++) {
            float val = acc[n][r] * dscale[r];
            float p = __shfl_xor(val, 1, 64);
            int row = rowBase + 16 * w + (l >> 4) * 4 + r;
            if (!(l & 1) && row < M)
                Y[(size_t)row * 64 + 8 * n + ((l & 15) >> 1)] = bf16pair(val, p);
        }
    }
}

// ---------------- small GEMM, N=5, K=128 (fp32 in/out) ----------------
__global__ void gemm_n5(const float* __restrict__ X, const float* __restrict__ W,
                        float* __restrict__ Y, int M) {
    int idx = blockIdx.x * 256 + threadIdx.x;
    int row = idx / 5, c = idx % 5;
    if (row >= M) return;
    float acc = 0.f;
#pragma unroll 8
    for (int k = 0; k < 128; k++) acc += X[row * 128 + k] * W[k * 5 + c];
    Y[row * 5 + c] = acc;
}

// ---------------- pack h5: fp32[5] * dinv[row] -> 8 bf16 (16B, padded) ----------------
__global__ void pack5(const float* __restrict__ Y, const float* __restrict__ dinv,
                      uint4* __restrict__ hc, int N) {
    int node = blockIdx.x * 256 + threadIdx.x;
    if (node >= N) return;
    float di = dinv[node];
    float v0 = Y[node * 5 + 0] * di;
    float v1 = Y[node * 5 + 1] * di;
    float v2 = Y[node * 5 + 2] * di;
    float v3 = Y[node * 5 + 3] * di;
    float v4 = Y[node * 5 + 4] * di;
    hc[node] = make_uint4(bf16pair(v0, v1), bf16pair(v2, v3), bf16pair(v4, 0.f), 0u);
}

// ---------------- CSR aggregation, dim 128: wave/node, 4 edges x 16 lanes x uint4 ----------------
__global__ __launch_bounds__(256) void agg128_v2(const uint4* __restrict__ hb4,
                                                 const int* __restrict__ rowptr,
                                                 const int* __restrict__ col,
                                                 const float* __restrict__ dinv,
                                                 const float* __restrict__ bias,
                                                 float* __restrict__ out, int N, int do_relu) {
    int wave = threadIdx.x >> 6;
    int lane = threadIdx.x & 63;
    int node = blockIdx.x * 4 + wave;
    if (node >= N) return;
    int g = lane >> 4;    // edge slot 0..3
    int q = lane & 15;    // dim-octet: dims [q*8, q*8+8)
    int beg = rowptr[node], end = rowptr[node + 1];
    float a0 = 0.f, a1 = 0.f, a2 = 0.f, a3 = 0.f, a4 = 0.f, a5 = 0.f, a6 = 0.f, a7 = 0.f;

    int j = beg;
    int e8 = beg + ((end - beg) & ~7);
    for (; j < e8; j += 8) {
        int s0 = col[j + g];
        int s1 = col[j + 4 + g];
        uint4 v0 = hb4[(size_t)s0 * 16 + q];
        uint4 v1 = hb4[(size_t)s1 * 16 + q];
        a0 += bflo(v0.x); a1 += bfhi(v0.x);
        a2 += bflo(v0.y); a3 += bfhi(v0.y);
        a4 += bflo(v0.z); a5 += bfhi(v0.z);
        a6 += bflo(v0.w); a7 += bfhi(v0.w);
        a0 += bflo(v1.x); a1 += bfhi(v1.x);
        a2 += bflo(v1.y); a3 += bfhi(v1.y);
        a4 += bflo(v1.z); a5 += bfhi(v1.z);
        a6 += bflo(v1.w); a7 += bfhi(v1.w);
    }
    if (j < end) {
        int jj0 = j + g, jj1 = j + 4 + g;
        bool p0 = jj0 < end, p1 = jj1 < end;
        int s0 = p0 ? col[jj0] : node;
        int s1 = p1 ? col[jj1] : node;
        uint4 v0 = hb4[(size_t)s0 * 16 + q];
        uint4 v1 = hb4[(size_t)s1 * 16 + q];
        if (!p0) v0 = make_uint4(0u, 0u, 0u, 0u);
        if (!p1) v1 = make_uint4(0u, 0u, 0u, 0u);
        a0 += bflo(v0.x); a1 += bfhi(v0.x);
        a2 += bflo(v0.y); a3 += bfhi(v0.y);
        a4 += bflo(v0.z); a5 += bfhi(v0.z);
        a6 += bflo(v0.w); a7 += bfhi(v0.w);
        a0 += bflo(v1.x); a1 += bfhi(v1.x);
        a2 += bflo(v1.y); a3 += bfhi(v1.y);
        a4 += bflo(v1.z); a5 += bfhi(v1.z);
        a6 += bflo(v1.w); a7 += bfhi(v1.w);
    }
    // reduce across the 4 edge-slot groups
#pragma unroll
    for (int off = 16; off <= 32; off <<= 1) {
        a0 += __shfl_xor(a0, off, 64);
        a1 += __shfl_xor(a1, off, 64);
        a2 += __shfl_xor(a2, off, 64);
        a3 += __shfl_xor(a3, off, 64);
        a4 += __shfl_xor(a4, off, 64);
        a5 += __shfl_xor(a5, off, 64);
        a6 += __shfl_xor(a6, off, 64);
        a7 += __shfl_xor(a7, off, 64);
    }
    if (g == 0) {
        // self term: hb4[node] is already dinv[node]*h[node]
        uint4 vs = hb4[(size_t)node * 16 + q];
        a0 += bflo(vs.x); a1 += bfhi(vs.x);
        a2 += bflo(vs.y); a3 += bfhi(vs.y);
        a4 += bflo(vs.z); a5 += bfhi(vs.z);
        a6 += bflo(vs.w); a7 += bfhi(vs.w);
        float di = dinv[node];
        const float4* bias4 = (const float4*)bias;
        float4 bb0 = bias4[q * 2], bb1 = bias4[q * 2 + 1];
        float o0 = a0 * di + bb0.x, o1 = a1 * di + bb0.y;
        float o2 = a2 * di + bb0.z, o3 = a3 * di + bb0.w;
        float o4 = a4 * di + bb1.x, o5 = a5 * di + bb1.y;
        float o6 = a6 * di + bb1.z, o7 = a7 * di + bb1.w;
        if (do_relu) {
            o0 = fmaxf(o0, 0.f); o1 = fmaxf(o1, 0.f);
            o2 = fmaxf(o2, 0.f); o3 = fmaxf(o3, 0.f);
            o4 = fmaxf(o4, 0.f); o5 = fmaxf(o5, 0.f);
            o6 = fmaxf(o6, 0.f); o7 = fmaxf(o7, 0.f);
        }
        float4* out4 = (float4*)out;
        out4[(size_t)node * 32 + q * 2] = make_float4(o0, o1, o2, o3);
        out4[(size_t)node * 32 + q * 2 + 1] = make_float4(o4, o5, o6, o7);
    }
}

// ---------------- CSR aggregation, dim 5 (packed bf16 rows): thread per node ----------------
__global__ void agg5_v2(const uint4* __restrict__ hc, const int* __restrict__ rowptr,
                        const int* __restrict__ col, const float* __restrict__ dinv,
                        const float* __restrict__ b3, float* __restrict__ out, int N) {
    int node = blockIdx.x * 256 + threadIdx.x;
    if (node >= N) return;
    float a0 = 0.f, a1 = 0.f, a2 = 0.f, a3 = 0.f, a4 = 0.f;
    int beg = rowptr[node], end = rowptr[node + 1];
#pragma unroll 2
    for (int j = beg; j < end; ++j) {
        uint4 v = hc[col[j]];
        a0 += bflo(v.x); a1 += bfhi(v.x);
        a2 += bflo(v.y); a3 += bfhi(v.y);
        a4 += bflo(v.z);
    }
    // self term (hc[node] pre-scaled by dinv)
    uint4 vs = hc[node];
    a0 += bflo(vs.x); a1 += bfhi(vs.x);
    a2 += bflo(vs.y); a3 += bfhi(vs.y);
    a4 += bflo(vs.z);
    float di = dinv[node];
    out[node * 5 + 0] = a0 * di + b3[0];
    out[node * 5 + 1] = a1 * di + b3[1];
    out[node * 5 + 2] = a2 * di + b3[2];
    out[node * 5 + 3] = a3 * di + b3[3];
    out[node * 5 + 4] = a4 * di + b3[4];
}

static inline size_t align512(size_t x) { return (x + 511) & ~(size_t)511; }

extern "C" void kernel_launch(void* const* d_in, const int* in_sizes, int n_in,
                              void* d_out, int out_size, void* d_ws, size_t ws_size,
                              hipStream_t stream) {
    const float* x  = (const float*)d_in[0];
    const int* ei   = (const int*)d_in[1];
    const float* W1 = (const float*)d_in[2];
    const float* b1 = (const float*)d_in[3];
    const float* W2 = (const float*)d_in[4];
    const float* b2 = (const float*)d_in[5];
    const float* W3 = (const float*)d_in[6];
    const float* b3 = (const float*)d_in[7];
    const int* src = ei;
    const int* dst = ei + NE;

    char* ws = (char*)d_ws;
    size_t off = 0;
    int* cnt = (int*)(ws + off);        off += align512((size_t)NN * 4);
    int* rowptr = (int*)(ws + off);     off += align512((size_t)(NN + 1) * 4);
    float* dinv = (float*)(ws + off);   off += align512((size_t)NN * 4);
    int* bsum = (int*)(ws + off);       off += align512((size_t)128 * 4);
    int* ghist = (int*)(ws + off);      off += align512((size_t)GH * 4);
    ushort* wt1h = (ushort*)(ws + off); off += align512((size_t)128 * 384 * 2);
    ushort* wt1l = (ushort*)(ws + off); off += align512((size_t)128 * 384 * 2);
    ushort* wt2h = (ushort*)(ws + off); off += align512((size_t)128 * 128 * 2);
    ushort* wt2l = (ushort*)(ws + off); off += align512((size_t)128 * 128 * 2);
    int* col = (int*)(ws + off);        off += align512((size_t)NE * 4);
    uint* hb = (uint*)(ws + off);       off += align512((size_t)NN * 64 * 4);   // bf16 dinv*h (packed)
    float* bufF = (float*)(ws + off);   off += align512((size_t)NN * 128 * 4);  // fp32 agg out
    float* bufC = (float*)(ws + off);   off += align512((size_t)NN * 5 * 4);
    uint4* hc = (uint4*)(ws + off);     off += align512((size_t)NN * 16);       // packed bf16 dinv*h5
    uint* binned = (uint*)bufF;  // alias: binned dead before bufF's first write
    (void)ws_size;

    // ---- W transpose + hi/lo split ----
    wsplit<384><<<12, 256, 0, stream>>>(W1, wt1h, wt1l);
    wsplit<128><<<4, 256, 0, stream>>>(W2, wt2h, wt2l);

    // ---- build CSR (by dst) + dinv, bucket-sorted for write locality ----
    hist_bkt<<<BIN_BLOCKS, 256, 0, stream>>>(dst, ghist);
    {
        int nb = (GH + SCAN_CHUNK - 1) / SCAN_CHUNK;  // 98
        scan_p1<<<nb, 256, 0, stream>>>(ghist, bsum, GH);
        scan_p2<<<1, 128, 0, stream>>>(bsum, nb);
        scan_p3_plain<<<nb, 256, 0, stream>>>(ghist, bsum, GH);
    }
    bin_edges<<<BIN_BLOCKS, 256, 0, stream>>>(src, dst, ghist, binned);
    bucket_count<<<NBKT, 256, 0, stream>>>(binned, ghist, cnt);
    {
        int nb = (NN + SCAN_CHUNK - 1) / SCAN_CHUNK;  // 98
        scan_p1<<<nb, 256, 0, stream>>>(cnt, bsum, NN);
        scan_p2<<<1, 128, 0, stream>>>(bsum, nb);
        scan_p3_deg<<<nb, 256, 0, stream>>>(cnt, bsum, rowptr, dinv, NN);
    }
    csr_fill<<<NBKT, 256, 0, stream>>>(binned, ghist, rowptr, col);

    int gemm_blocks = (NN + 63) / 64;  // 1563
    // ---- layer 1 ----
    mfma_gemm<384><<<gemm_blocks, 256, 0, stream>>>(x, wt1h, wt1l, dinv, hb, NN);
    agg128_v2<<<(NN + 3) / 4, 256, 0, stream>>>((const uint4*)hb, rowptr, col, dinv, b1, bufF, NN, 1);
    // ---- layer 2 ----
    mfma_gemm<128><<<gemm_blocks, 256, 0, stream>>>(bufF, wt2h, wt2l, dinv, hb, NN);
    agg128_v2<<<(NN + 3) / 4, 256, 0, stream>>>((const uint4*)hb, rowptr, col, dinv, b2, bufF, NN, 1);
    // ---- layer 3 ----
    gemm_n5<<<((NN * 5) + 255) / 256, 256, 0, stream>>>(bufF, W3, bufC, NN);
    pack5<<<(NN + 255) / 256, 256, 0, stream>>>(bufC, dinv, hc, NN);
    agg5_v2<<<(NN + 255) / 256, 256, 0, stream>>>(hc, rowptr, col, dinv, b3, (float*)d_out, NN);
}

// Round 7
// 492.268 us; speedup vs baseline: 2.8605x; 1.0064x over previous
//
#include <hip/hip_runtime.h>

#define NN 100000
#define NE 3200000
#define SCAN_CHUNK 1024

// bucket sort params
#define BSH 8
#define BKT_NODES 256                       // 1 << BSH
#define NBKT ((NN + BKT_NODES - 1) / BKT_NODES)   // 391
#define BIN_BLOCKS 256
#define EPB ((NE + BIN_BLOCKS - 1) / BIN_BLOCKS)  // 12500
#define GH (NBKT * BIN_BLOCKS)                    // 100096

typedef unsigned int uint;
typedef unsigned short ushort;
typedef __attribute__((ext_vector_type(8))) short short8;
typedef __attribute__((ext_vector_type(4))) float f32x4;

// round fp32 -> bf16 (RNE), return upper 16 bits
__device__ inline ushort bf16rne(float x) {
    uint u = __float_as_uint(x);
    u += 0x7FFFu + ((u >> 16) & 1u);
    return (ushort)(u >> 16);
}
// split x into hi bf16 + lo bf16 (x ~= hi + lo)
__device__ inline void split2(float x, ushort& h, ushort& l) {
    h = bf16rne(x);
    float hf = __uint_as_float((uint)h << 16);
    l = bf16rne(x - hf);
}
// pack two fp32 -> two bf16 (RNE) in one uint (a = low, b = high)
__device__ inline uint bf16pair(float a, float b) {
    uint ua = __float_as_uint(a);
    uint ub = __float_as_uint(b);
    ua += 0x7FFFu + ((ua >> 16) & 1u);
    ub += 0x7FFFu + ((ub >> 16) & 1u);
    return (ua >> 16) | (ub & 0xFFFF0000u);
}
__device__ inline float bflo(uint u) { return __uint_as_float(u << 16); }
__device__ inline float bfhi(uint u) { return __uint_as_float(u & 0xFFFF0000u); }

// ---------------- bucket histogram ----------------
__global__ __launch_bounds__(256) void hist_bkt(const int* __restrict__ dst,
                                                int* __restrict__ ghist) {
    __shared__ int h[NBKT];
    int t = threadIdx.x;
    for (int i = t; i < NBKT; i += 256) h[i] = 0;
    __syncthreads();
    int beg = blockIdx.x * EPB;
    int end = beg + EPB; if (end > NE) end = NE;
    for (int e = beg + t; e < end; e += 256)
        atomicAdd(&h[dst[e] >> BSH], 1);
    __syncthreads();
    for (int i = t; i < NBKT; i += 256)
        ghist[i * BIN_BLOCKS + blockIdx.x] = h[i];
}

// ---------------- hierarchical scan: phase 1 ----------------
__global__ __launch_bounds__(256) void scan_p1(const int* __restrict__ cnt,
                                               int* __restrict__ bsum, int N) {
    int t = threadIdx.x;
    int base = blockIdx.x * SCAN_CHUNK + t * 4;
    int s = 0;
#pragma unroll
    for (int q = 0; q < 4; q++) {
        int i = base + q;
        if (i < N) s += cnt[i];
    }
    __shared__ int red[4];
#pragma unroll
    for (int off = 32; off; off >>= 1) s += __shfl_down(s, off, 64);
    if ((t & 63) == 0) red[t >> 6] = s;
    __syncthreads();
    if (t == 0) bsum[blockIdx.x] = red[0] + red[1] + red[2] + red[3];
}

// ---------------- phase 2 ----------------
__global__ void scan_p2(int* __restrict__ bsum, int nb) {
    __shared__ int s[128];
    int t = threadIdx.x;
    int v = (t < nb) ? bsum[t] : 0;
    s[t] = v;
    __syncthreads();
    for (int off = 1; off < 128; off <<= 1) {
        int x = s[t];
        int add = (t >= off) ? s[t - off] : 0;
        __syncthreads();
        s[t] = x + add;
        __syncthreads();
    }
    if (t < nb) bsum[t] = s[t] - v;  // exclusive
}

// ---------------- phase 3a: in-place exclusive scan ----------------
__global__ __launch_bounds__(256) void scan_p3_plain(int* __restrict__ data,
                                                     const int* __restrict__ bsum, int N) {
    __shared__ int ts[256];
    int t = threadIdx.x;
    int base = blockIdx.x * SCAN_CHUNK + t * 4;
    int c[4];
    int s = 0;
#pragma unroll
    for (int q = 0; q < 4; q++) {
        int i = base + q;
        c[q] = (i < N) ? data[i] : 0;
        s += c[q];
    }
    ts[t] = s;
    __syncthreads();
    for (int off = 1; off < 256; off <<= 1) {
        int x = ts[t];
        int add = (t >= off) ? ts[t - off] : 0;
        __syncthreads();
        ts[t] = x + add;
        __syncthreads();
    }
    int run = bsum[blockIdx.x] + ts[t] - s;
#pragma unroll
    for (int q = 0; q < 4; q++) {
        int i = base + q;
        if (i < N) { data[i] = run; run += c[q]; }
    }
}

// ---------------- phase 3b: scan + rowptr + dinv ----------------
__global__ __launch_bounds__(256) void scan_p3_deg(const int* __restrict__ cnt,
                                                   const int* __restrict__ bsum,
                                                   int* __restrict__ rowptr,
                                                   float* __restrict__ dinv, int N) {
    __shared__ int ts[256];
    int t = threadIdx.x;
    int base = blockIdx.x * SCAN_CHUNK + t * 4;
    int c[4];
    int s = 0;
#pragma unroll
    for (int q = 0; q < 4; q++) {
        int i = base + q;
        c[q] = (i < N) ? cnt[i] : 0;
        s += c[q];
    }
    ts[t] = s;
    __syncthreads();
    for (int off = 1; off < 256; off <<= 1) {
        int x = ts[t];
        int add = (t >= off) ? ts[t - off] : 0;
        __syncthreads();
        ts[t] = x + add;
        __syncthreads();
    }
    int run = bsum[blockIdx.x] + ts[t] - s;
#pragma unroll
    for (int q = 0; q < 4; q++) {
        int i = base + q;
        if (i < N) {
            rowptr[i] = run;
            dinv[i] = 1.0f / sqrtf((float)(c[q] + 1));  // +1 self-loop
            run += c[q];
        }
    }
    if (base < N && N <= base + 4) rowptr[N] = run;
}

// ---------------- bin edges into bucket-segmented records ----------------
__global__ __launch_bounds__(256) void bin_edges(const int* __restrict__ src,
                                                 const int* __restrict__ dst,
                                                 const int* __restrict__ ghist,
                                                 uint* __restrict__ binned) {
    __shared__ int cur[NBKT];
    int t = threadIdx.x;
    for (int i = t; i < NBKT; i += 256) cur[i] = ghist[i * BIN_BLOCKS + blockIdx.x];
    __syncthreads();
    int beg = blockIdx.x * EPB;
    int end = beg + EPB; if (end > NE) end = NE;
    for (int e = beg + t; e < end; e += 256) {
        int d = dst[e];
        int b = d >> BSH;
        int p = atomicAdd(&cur[b], 1);
        binned[p] = ((uint)src[e] << BSH) | (uint)(d & (BKT_NODES - 1));
    }
}

// ---------------- per-bucket node degree count ----------------
__global__ __launch_bounds__(256) void bucket_count(const uint* __restrict__ binned,
                                                    const int* __restrict__ ghist,
                                                    int* __restrict__ cnt) {
    __shared__ int c[BKT_NODES];
    int t = threadIdx.x;
    int bkt = blockIdx.x;
    for (int i = t; i < BKT_NODES; i += 256) c[i] = 0;
    __syncthreads();
    int beg = ghist[bkt * BIN_BLOCKS];
    int end = (bkt == NBKT - 1) ? NE : ghist[(bkt + 1) * BIN_BLOCKS];
    for (int j = beg + t; j < end; j += 256)
        atomicAdd(&c[binned[j] & (BKT_NODES - 1)], 1);
    __syncthreads();
    int base = bkt * BKT_NODES;
    int nb = NN - base; if (nb > BKT_NODES) nb = BKT_NODES;
    for (int i = t; i < nb; i += 256) cnt[base + i] = c[i];
}

// ---------------- per-bucket CSR fill ----------------
__global__ __launch_bounds__(256) void csr_fill(const uint* __restrict__ binned,
                                                const int* __restrict__ ghist,
                                                const int* __restrict__ rowptr,
                                                int* __restrict__ col) {
    __shared__ int fill[BKT_NODES];
    int t = threadIdx.x;
    int bkt = blockIdx.x;
    for (int i = t; i < BKT_NODES; i += 256) fill[i] = 0;
    __syncthreads();
    int beg = ghist[bkt * BIN_BLOCKS];
    int end = (bkt == NBKT - 1) ? NE : ghist[(bkt + 1) * BIN_BLOCKS];
    int base = bkt * BKT_NODES;
    for (int j = beg + t; j < end; j += 256) {
        uint r = binned[j];
        int dl = r & (BKT_NODES - 1);
        int p = rowptr[base + dl] + atomicAdd(&fill[dl], 1);
        col[p] = (int)(r >> BSH);
    }
}

// ---------------- W transpose + bf16 hi/lo split: W[K][128] -> Wt[128][K] ----------------
template <int K>
__global__ __launch_bounds__(256) void wsplit(const float* __restrict__ W,
                                              ushort* __restrict__ Wth,
                                              ushort* __restrict__ Wtl) {
    __shared__ float tile[32][128];
    int t = threadIdx.x;
    int kb = blockIdx.x;
    {
        int k = t >> 3, cq = t & 7;
#pragma unroll
        for (int q = 0; q < 4; q++) {
            float4 v = *(const float4*)&W[(size_t)(kb * 32 + k) * 128 + cq * 16 + q * 4];
            *(float4*)&tile[k][cq * 16 + q * 4] = v;
        }
    }
    __syncthreads();
    {
        int c = t >> 1, g = t & 1;
        ushort hs[16], ls[16];
#pragma unroll
        for (int i = 0; i < 16; i++) split2(tile[g * 16 + i][c], hs[i], ls[i]);
        uint h[8], lo[8];
#pragma unroll
        for (int i = 0; i < 8; i++) {
            h[i] = (uint)hs[2 * i] | ((uint)hs[2 * i + 1] << 16);
            lo[i] = (uint)ls[2 * i] | ((uint)ls[2 * i + 1] << 16);
        }
        size_t o = (size_t)c * K + kb * 32 + g * 16;
        *(uint4*)&Wth[o] = make_uint4(h[0], h[1], h[2], h[3]);
        *(uint4*)&Wth[o + 8] = make_uint4(h[4], h[5], h[6], h[7]);
        *(uint4*)&Wtl[o] = make_uint4(lo[0], lo[1], lo[2], lo[3]);
        *(uint4*)&Wtl[o + 8] = make_uint4(lo[4], lo[5], lo[6], lo[7]);
    }
}

// ---------------- MFMA GEMM: X @ Wt (bf16x3) -> hb packed bf16, PRE-SCALED by dinv[row] ----------------
template <int K>
__global__ __launch_bounds__(256) void mfma_gemm(const float* __restrict__ X,
                                                 const ushort* __restrict__ Wth,
                                                 const ushort* __restrict__ Wtl,
                                                 const float* __restrict__ dinv,
                                                 uint* __restrict__ Y, int M) {
    __shared__ char smem[24 * 1024];
    char* aHi = smem;
    char* aLo = smem + 4096;
    char* bHi = smem + 8192;
    char* bLo = smem + 16384;
    int tid = threadIdx.x;
    int w = tid >> 6, l = tid & 63;
    int rowBase = blockIdx.x * 64;

    f32x4 acc[8];
#pragma unroll
    for (int n = 0; n < 8; n++) acc[n] = (f32x4){0.f, 0.f, 0.f, 0.f};

    int sRow = tid >> 2, sKg = tid & 3;
    int gRowA = rowBase + sRow;
    int fKg = l >> 4;
    int aOff = fKg * 1024 + ((16 * w + (l & 15)) ^ fKg) * 16;

    for (int kt = 0; kt < K; kt += 32) {
        {
            float v[8];
            if (gRowA < M) {
                float4 p0 = *(const float4*)&X[(size_t)gRowA * K + kt + sKg * 8];
                float4 p1 = *(const float4*)&X[(size_t)gRowA * K + kt + sKg * 8 + 4];
                v[0] = p0.x; v[1] = p0.y; v[2] = p0.z; v[3] = p0.w;
                v[4] = p1.x; v[5] = p1.y; v[6] = p1.z; v[7] = p1.w;
            } else {
#pragma unroll
                for (int i = 0; i < 8; i++) v[i] = 0.f;
            }
            uint hh[4], hl[4];
#pragma unroll
            for (int i = 0; i < 4; i++) {
                ushort h0, l0, h1, l1;
                split2(v[2 * i], h0, l0);
                split2(v[2 * i + 1], h1, l1);
                hh[i] = (uint)h0 | ((uint)h1 << 16);
                hl[i] = (uint)l0 | ((uint)l1 << 16);
            }
            int wa = sKg * 1024 + ((sRow ^ sKg) * 16);
            *(uint4*)(aHi + wa) = make_uint4(hh[0], hh[1], hh[2], hh[3]);
            *(uint4*)(aLo + wa) = make_uint4(hl[0], hl[1], hl[2], hl[3]);
        }
#pragma unroll
        for (int i = 0; i < 2; i++) {
            int ci = tid + i * 256;
            int colb = ci >> 2, kg = ci & 3;
            uint4 vh = *(const uint4*)&Wth[(size_t)colb * K + kt + kg * 8];
            uint4 vl = *(const uint4*)&Wtl[(size_t)colb * K + kt + kg * 8];
            int wb = kg * 2048 + ((colb ^ kg) * 16);
            *(uint4*)(bHi + wb) = vh;
            *(uint4*)(bLo + wb) = vl;
        }
        __syncthreads();
        short8 ah = *(const short8*)(aHi + aOff);
        short8 al = *(const short8*)(aLo + aOff);
#pragma unroll
        for (int n = 0; n < 8; n++) {
            int bOff = fKg * 2048 + ((16 * n + (l & 15)) ^ fKg) * 16;
            short8 bh = *(const short8*)(bHi + bOff);
            short8 bl = *(const short8*)(bLo + bOff);
            acc[n] = __builtin_amdgcn_mfma_f32_16x16x32_bf16(ah, bh, acc[n], 0, 0, 0);
            acc[n] = __builtin_amdgcn_mfma_f32_16x16x32_bf16(ah, bl, acc[n], 0, 0, 0);
            acc[n] = __builtin_amdgcn_mfma_f32_16x16x32_bf16(al, bh, acc[n], 0, 0, 0);
        }
        __syncthreads();
    }
    // dinv scales for this thread's 4 rows
    float dscale[4];
#pragma unroll
    for (int r = 0; r < 4; r++) {
        int row = rowBase + 16 * w + (l >> 4) * 4 + r;
        dscale[r] = (row < M) ? dinv[row] : 0.f;
    }
    // epilogue: D[row][col] scaled -> packed bf16 pairs
#pragma unroll
    for (int n = 0; n < 8; n++) {
#pragma unroll
        for (int r = 0; r < 4; r++) {
            float val = acc[n][r] * dscale[r];
            float p = __shfl_xor(val, 1, 64);
            int row = rowBase + 16 * w + (l >> 4) * 4 + r;
            if (!(l & 1) && row < M)
                Y[(size_t)row * 64 + 8 * n + ((l & 15) >> 1)] = bf16pair(val, p);
        }
    }
}

// ---------------- small GEMM, N=5, K=128 (fp32 in/out) ----------------
__global__ void gemm_n5(const float* __restrict__ X, const float* __restrict__ W,
                        float* __restrict__ Y, int M) {
    int idx = blockIdx.x * 256 + threadIdx.x;
    int row = idx / 5, c = idx % 5;
    if (row >= M) return;
    float acc = 0.f;
#pragma unroll 8
    for (int k = 0; k < 128; k++) acc += X[row * 128 + k] * W[k * 5 + c];
    Y[row * 5 + c] = acc;
}

// ---------------- pack h5: fp32[5] * dinv[row] -> 8 bf16 (16B, padded) ----------------
__global__ void pack5(const float* __restrict__ Y, const float* __restrict__ dinv,
                      uint4* __restrict__ hc, int N) {
    int node = blockIdx.x * 256 + threadIdx.x;
    if (node >= N) return;
    float di = dinv[node];
    float v0 = Y[node * 5 + 0] * di;
    float v1 = Y[node * 5 + 1] * di;
    float v2 = Y[node * 5 + 2] * di;
    float v3 = Y[node * 5 + 3] * di;
    float v4 = Y[node * 5 + 4] * di;
    hc[node] = make_uint4(bf16pair(v0, v1), bf16pair(v2, v3), bf16pair(v4, 0.f), 0u);
}

#define ACC8(v)                         \
    a0 += bflo(v.x); a1 += bfhi(v.x);   \
    a2 += bflo(v.y); a3 += bfhi(v.y);   \
    a4 += bflo(v.z); a5 += bfhi(v.z);   \
    a6 += bflo(v.w); a7 += bfhi(v.w);

// ---------------- CSR aggregation, dim 128: wave/node, deep-unrolled gathers ----------------
__global__ __launch_bounds__(256) void agg128_v3(const uint4* __restrict__ hb4,
                                                 const int* __restrict__ rowptr,
                                                 const int* __restrict__ col,
                                                 const float* __restrict__ dinv,
                                                 const float* __restrict__ bias,
                                                 float* __restrict__ out, int N, int do_relu) {
    int wave = threadIdx.x >> 6;
    int lane = threadIdx.x & 63;
    int node = blockIdx.x * 4 + wave;
    if (node >= N) return;
    int g = lane >> 4;    // edge slot 0..3
    int q = lane & 15;    // dim-octet: dims [q*8, q*8+8)
    int beg = rowptr[node], end = rowptr[node + 1];
    float a0 = 0.f, a1 = 0.f, a2 = 0.f, a3 = 0.f, a4 = 0.f, a5 = 0.f, a6 = 0.f, a7 = 0.f;

    int j = beg;
    // 16-edge unrolled main loop: 4 independent gathers in flight per wave
    for (; j + 16 <= end; j += 16) {
        int s0 = col[j + g];
        int s1 = col[j + 4 + g];
        int s2 = col[j + 8 + g];
        int s3 = col[j + 12 + g];
        uint4 v0 = hb4[(size_t)s0 * 16 + q];
        uint4 v1 = hb4[(size_t)s1 * 16 + q];
        uint4 v2 = hb4[(size_t)s2 * 16 + q];
        uint4 v3 = hb4[(size_t)s3 * 16 + q];
        ACC8(v0); ACC8(v1); ACC8(v2); ACC8(v3);
    }
    // 8-edge step
    if (j + 8 <= end) {
        int s0 = col[j + g];
        int s1 = col[j + 4 + g];
        uint4 v0 = hb4[(size_t)s0 * 16 + q];
        uint4 v1 = hb4[(size_t)s1 * 16 + q];
        ACC8(v0); ACC8(v1);
        j += 8;
    }
    // masked tail (<8 edges)
    if (j < end) {
        int jj0 = j + g, jj1 = j + 4 + g;
        bool p0 = jj0 < end, p1 = jj1 < end;
        int s0 = p0 ? col[jj0] : node;
        int s1 = p1 ? col[jj1] : node;
        uint4 v0 = hb4[(size_t)s0 * 16 + q];
        uint4 v1 = hb4[(size_t)s1 * 16 + q];
        if (!p0) v0 = make_uint4(0u, 0u, 0u, 0u);
        if (!p1) v1 = make_uint4(0u, 0u, 0u, 0u);
        ACC8(v0); ACC8(v1);
    }
    // reduce across the 4 edge-slot groups
#pragma unroll
    for (int off = 16; off <= 32; off <<= 1) {
        a0 += __shfl_xor(a0, off, 64);
        a1 += __shfl_xor(a1, off, 64);
        a2 += __shfl_xor(a2, off, 64);
        a3 += __shfl_xor(a3, off, 64);
        a4 += __shfl_xor(a4, off, 64);
        a5 += __shfl_xor(a5, off, 64);
        a6 += __shfl_xor(a6, off, 64);
        a7 += __shfl_xor(a7, off, 64);
    }
    if (g == 0) {
        // self term: hb4[node] is already dinv[node]*h[node]
        uint4 vs = hb4[(size_t)node * 16 + q];
        ACC8(vs);
        float di = dinv[node];
        const float4* bias4 = (const float4*)bias;
        float4 bb0 = bias4[q * 2], bb1 = bias4[q * 2 + 1];
        float o0 = a0 * di + bb0.x, o1 = a1 * di + bb0.y;
        float o2 = a2 * di + bb0.z, o3 = a3 * di + bb0.w;
        float o4 = a4 * di + bb1.x, o5 = a5 * di + bb1.y;
        float o6 = a6 * di + bb1.z, o7 = a7 * di + bb1.w;
        if (do_relu) {
            o0 = fmaxf(o0, 0.f); o1 = fmaxf(o1, 0.f);
            o2 = fmaxf(o2, 0.f); o3 = fmaxf(o3, 0.f);
            o4 = fmaxf(o4, 0.f); o5 = fmaxf(o5, 0.f);
            o6 = fmaxf(o6, 0.f); o7 = fmaxf(o7, 0.f);
        }
        float4* out4 = (float4*)out;
        out4[(size_t)node * 32 + q * 2] = make_float4(o0, o1, o2, o3);
        out4[(size_t)node * 32 + q * 2 + 1] = make_float4(o4, o5, o6, o7);
    }
}

// ---------------- CSR aggregation, dim 5 (packed bf16 rows): thread per node ----------------
__global__ void agg5_v2(const uint4* __restrict__ hc, const int* __restrict__ rowptr,
                        const int* __restrict__ col, const float* __restrict__ dinv,
                        const float* __restrict__ b3, float* __restrict__ out, int N) {
    int node = blockIdx.x * 256 + threadIdx.x;
    if (node >= N) return;
    float a0 = 0.f, a1 = 0.f, a2 = 0.f, a3 = 0.f, a4 = 0.f;
    int beg = rowptr[node], end = rowptr[node + 1];
#pragma unroll 2
    for (int j = beg; j < end; ++j) {
        uint4 v = hc[col[j]];
        a0 += bflo(v.x); a1 += bfhi(v.x);
        a2 += bflo(v.y); a3 += bfhi(v.y);
        a4 += bflo(v.z);
    }
    // self term (hc[node] pre-scaled by dinv)
    uint4 vs = hc[node];
    a0 += bflo(vs.x); a1 += bfhi(vs.x);
    a2 += bflo(vs.y); a3 += bfhi(vs.y);
    a4 += bflo(vs.z);
    float di = dinv[node];
    out[node * 5 + 0] = a0 * di + b3[0];
    out[node * 5 + 1] = a1 * di + b3[1];
    out[node * 5 + 2] = a2 * di + b3[2];
    out[node * 5 + 3] = a3 * di + b3[3];
    out[node * 5 + 4] = a4 * di + b3[4];
}

static inline size_t align512(size_t x) { return (x + 511) & ~(size_t)511; }

extern "C" void kernel_launch(void* const* d_in, const int* in_sizes, int n_in,
                              void* d_out, int out_size, void* d_ws, size_t ws_size,
                              hipStream_t stream) {
    const float* x  = (const float*)d_in[0];
    const int* ei   = (const int*)d_in[1];
    const float* W1 = (const float*)d_in[2];
    const float* b1 = (const float*)d_in[3];
    const float* W2 = (const float*)d_in[4];
    const float* b2 = (const float*)d_in[5];
    const float* W3 = (const float*)d_in[6];
    const float* b3 = (const float*)d_in[7];
    const int* src = ei;
    const int* dst = ei + NE;

    char* ws = (char*)d_ws;
    size_t off = 0;
    int* cnt = (int*)(ws + off);        off += align512((size_t)NN * 4);
    int* rowptr = (int*)(ws + off);     off += align512((size_t)(NN + 1) * 4);
    float* dinv = (float*)(ws + off);   off += align512((size_t)NN * 4);
    int* bsum = (int*)(ws + off);       off += align512((size_t)128 * 4);
    int* ghist = (int*)(ws + off);      off += align512((size_t)GH * 4);
    ushort* wt1h = (ushort*)(ws + off); off += align512((size_t)128 * 384 * 2);
    ushort* wt1l = (ushort*)(ws + off); off += align512((size_t)128 * 384 * 2);
    ushort* wt2h = (ushort*)(ws + off); off += align512((size_t)128 * 128 * 2);
    ushort* wt2l = (ushort*)(ws + off); off += align512((size_t)128 * 128 * 2);
    int* col = (int*)(ws + off);        off += align512((size_t)NE * 4);
    uint* hb = (uint*)(ws + off);       off += align512((size_t)NN * 64 * 4);   // bf16 dinv*h (packed)
    float* bufF = (float*)(ws + off);   off += align512((size_t)NN * 128 * 4);  // fp32 agg out
    float* bufC = (float*)(ws + off);   off += align512((size_t)NN * 5 * 4);
    uint4* hc = (uint4*)(ws + off);     off += align512((size_t)NN * 16);       // packed bf16 dinv*h5
    uint* binned = (uint*)bufF;  // alias: binned dead before bufF's first write
    (void)ws_size;

    // ---- W transpose + hi/lo split ----
    wsplit<384><<<12, 256, 0, stream>>>(W1, wt1h, wt1l);
    wsplit<128><<<4, 256, 0, stream>>>(W2, wt2h, wt2l);

    // ---- build CSR (by dst) + dinv, bucket-sorted for write locality ----
    hist_bkt<<<BIN_BLOCKS, 256, 0, stream>>>(dst, ghist);
    {
        int nb = (GH + SCAN_CHUNK - 1) / SCAN_CHUNK;  // 98
        scan_p1<<<nb, 256, 0, stream>>>(ghist, bsum, GH);
        scan_p2<<<1, 128, 0, stream>>>(bsum, nb);
        scan_p3_plain<<<nb, 256, 0, stream>>>(ghist, bsum, GH);
    }
    bin_edges<<<BIN_BLOCKS, 256, 0, stream>>>(src, dst, ghist, binned);
    bucket_count<<<NBKT, 256, 0, stream>>>(binned, ghist, cnt);
    {
        int nb = (NN + SCAN_CHUNK - 1) / SCAN_CHUNK;  // 98
        scan_p1<<<nb, 256, 0, stream>>>(cnt, bsum, NN);
        scan_p2<<<1, 128, 0, stream>>>(bsum, nb);
        scan_p3_deg<<<nb, 256, 0, stream>>>(cnt, bsum, rowptr, dinv, NN);
    }
    csr_fill<<<NBKT, 256, 0, stream>>>(binned, ghist, rowptr, col);

    int gemm_blocks = (NN + 63) / 64;  // 1563
    // ---- layer 1 ----
    mfma_gemm<384><<<gemm_blocks, 256, 0, stream>>>(x, wt1h, wt1l, dinv, hb, NN);
    agg128_v3<<<(NN + 3) / 4, 256, 0, stream>>>((const uint4*)hb, rowptr, col, dinv, b1, bufF, NN, 1);
    // ---- layer 2 ----
    mfma_gemm<128><<<gemm_blocks, 256, 0, stream>>>(bufF, wt2h, wt2l, dinv, hb, NN);
    agg128_v3<<<(NN + 3) / 4, 256, 0, stream>>>((const uint4*)hb, rowptr, col, dinv, b2, bufF, NN, 1);
    // ---- layer 3 ----
    gemm_n5<<<((NN * 5) + 255) / 256, 256, 0, stream>>>(bufF, W3, bufC, NN);
    pack5<<<(NN + 255) / 256, 256, 0, stream>>>(bufC, dinv, hc, NN);
    agg5_v2<<<(NN + 255) / 256, 256, 0, stream>>>(hc, rowptr, col, dinv, b3, (float*)d_out, NN);
}